// Round 13
// baseline (259.688 us; speedup 1.0000x reference)
//
#include <hip/hip_runtime.h>
#include <math.h>

#define Dm    256
#define NHm   8
#define DHm   32
#define NLEVm 4
#define NPTSm 4
#define DFFNm 1024
#define Bm    8
#define LQm   900
#define LENm  13294
#define MQ    (Bm * LQm)      // 7200
#define MV    (Bm * LENm)     // 106352
#define MQP   7296            // MQ padded to 128
#define MVP   106368          // MV padded to 128
#define LQP   960             // keys padded to 15*64

typedef __attribute__((ext_vector_type(8))) short short8;   // 8 bf16 (4 VGPRs)
typedef __attribute__((ext_vector_type(4))) float f32x4;    // MFMA acc

__device__ __forceinline__ unsigned short f2bf(float f) {
    unsigned int b = __float_as_uint(f);
    unsigned int r = (b + 0x7FFFu + ((b >> 16) & 1u)) >> 16;
    return (unsigned short)r;
}
__device__ __forceinline__ float bf2f(unsigned short u) {
    return __uint_as_float(((unsigned int)u) << 16);
}

// -------------------- fused weight transposes + prep (one launch) -----------
__device__ __forceinline__ void wt_tile(const float* __restrict__ W,
                                        unsigned short* __restrict__ BT,
                                        int N, int K, int n0, int k0, int t,
                                        float (*tile)[65]) {
    #pragma unroll
    for (int r0 = 0; r0 < 64; r0 += 16) {
        int r = r0 + (t >> 4);
        int c = (t & 15) * 4;
        float4 v = *reinterpret_cast<const float4*>(W + (size_t)(k0 + r) * N + n0 + c);
        tile[r][c + 0] = v.x; tile[r][c + 1] = v.y; tile[r][c + 2] = v.z; tile[r][c + 3] = v.w;
    }
    __syncthreads();
    #pragma unroll
    for (int s = t; s < 512; s += 256) {
        int r = s >> 3, c8 = (s & 7) * 8;
        short8 u;
        #pragma unroll
        for (int j = 0; j < 8; ++j) u[j] = (short)f2bf(tile[c8 + j][r]);
        *reinterpret_cast<short8*>(BT + (size_t)(n0 + r) * K + k0 + c8) = u;
    }
}

__global__ __launch_bounds__(256) void wt_prep(
        const float* __restrict__ qkv_w, const float* __restrict__ out_w,
        const float* __restrict__ val_w, const float* __restrict__ off_w,
        const float* __restrict__ aw_w,  const float* __restrict__ op_w,
        const float* __restrict__ w1,    const float* __restrict__ w2,
        unsigned short* __restrict__ BT_qkv, unsigned short* __restrict__ BT_out,
        unsigned short* __restrict__ BT_val, unsigned short* __restrict__ BT_off,
        unsigned short* __restrict__ BT_aw,  unsigned short* __restrict__ BT_op,
        unsigned short* __restrict__ BT_w1,  unsigned short* __restrict__ BT_w2,
        const float* __restrict__ tgt, const float* __restrict__ qpos,
        unsigned short* __restrict__ tgtb, unsigned short* __restrict__ qb) {
    __shared__ float tile[64][65];
    int bid = blockIdx.x;
    int t = threadIdx.x;
    if (bid >= 248) {                        // prep: tgt_bf + Qbf
        int i = (bid - 248) * 256 + t;       // < 466944 = MQP*64
        ushort4 ut, uq;
        if (i < MQ * 64) {
            float4 x = reinterpret_cast<const float4*>(tgt)[i];
            float4 y = reinterpret_cast<const float4*>(qpos)[i];
            ut.x = f2bf(x.x); ut.y = f2bf(x.y); ut.z = f2bf(x.z); ut.w = f2bf(x.w);
            uq.x = f2bf(x.x + y.x); uq.y = f2bf(x.y + y.y);
            uq.z = f2bf(x.z + y.z); uq.w = f2bf(x.w + y.w);
        } else {
            ut.x = ut.y = ut.z = ut.w = 0;
            uq.x = uq.y = uq.z = uq.w = 0;
        }
        reinterpret_cast<ushort4*>(tgtb)[i] = ut;
        reinterpret_cast<ushort4*>(qb)[i] = uq;
        return;
    }
    const float* W; unsigned short* BT; int N, K, idx;
    if      (bid < 48)  { W = qkv_w; BT = BT_qkv; N = 768;  K = 256;  idx = bid; }
    else if (bid < 64)  { W = out_w; BT = BT_out; N = 256;  K = 256;  idx = bid - 48; }
    else if (bid < 80)  { W = val_w; BT = BT_val; N = 256;  K = 256;  idx = bid - 64; }
    else if (bid < 96)  { W = off_w; BT = BT_off; N = 256;  K = 256;  idx = bid - 80; }
    else if (bid < 104) { W = aw_w;  BT = BT_aw;  N = 128;  K = 256;  idx = bid - 96; }
    else if (bid < 120) { W = op_w;  BT = BT_op;  N = 256;  K = 256;  idx = bid - 104; }
    else if (bid < 184) { W = w1;    BT = BT_w1;  N = 1024; K = 256;  idx = bid - 120; }
    else                { W = w2;    BT = BT_w2;  N = 256;  K = 1024; idx = bid - 184; }
    int nt = N / 64;
    int n0 = (idx % nt) * 64, k0 = (idx / nt) * 64;
    wt_tile(W, BT, N, K, n0, k0, t, tile);
}

// -------------------- shared MFMA helpers ----------------------------------
__device__ __forceinline__ void mfma_tilestep(const unsigned short* Ac, const unsigned short* Bc,
                                              int wr, int wc, int l, f32x4 acc[4][4]) {
    short8 af[4], bfr[4];
    #pragma unroll
    for (int m = 0; m < 4; ++m)
        af[m] = *(const short8*)(Ac + (wr + m * 16 + (l & 15)) * 32 + (l >> 4) * 8);
    #pragma unroll
    for (int n = 0; n < 4; ++n)
        bfr[n] = *(const short8*)(Bc + (wc + n * 16 + (l & 15)) * 32 + (l >> 4) * 8);
    #pragma unroll
    for (int m = 0; m < 4; ++m)
        #pragma unroll
        for (int n = 0; n < 4; ++n)
            acc[m][n] = __builtin_amdgcn_mfma_f32_16x16x32_bf16(af[m], bfr[n], acc[m][n], 0, 0, 0);
}

// bf16 K=256 double-buffered main loop; Sh = 16384 ushorts (32 KB)
__device__ __forceinline__ void bf16_mainloop(int t, const unsigned short* __restrict__ Ag,
                                              const unsigned short* __restrict__ Bg,
                                              unsigned short* Sh, f32x4 acc[4][4]) {
    int l = t & 63, w = t >> 6;
    int wr = (w >> 1) * 64, wc = (w & 1) * 64;
    int s0 = t, s1 = t + 256;
    const unsigned short* a0p = Ag + (size_t)(s0 >> 2) * 256 + (s0 & 3) * 8;
    const unsigned short* a1p = Ag + (size_t)(s1 >> 2) * 256 + (s1 & 3) * 8;
    const unsigned short* b0p = Bg + (size_t)(s0 >> 2) * 256 + (s0 & 3) * 8;
    const unsigned short* b1p = Bg + (size_t)(s1 >> 2) * 256 + (s1 & 3) * 8;
    short8 ra0 = *(const short8*)(a0p);
    short8 ra1 = *(const short8*)(a1p);
    short8 rb0 = *(const short8*)(b0p);
    short8 rb1 = *(const short8*)(b1p);
    int cur = 0;
    for (int k0 = 0; k0 < 256; k0 += 32) {
        unsigned short* Ac = Sh + cur * 4096;
        unsigned short* Bc = Sh + 8192 + cur * 4096;
        *(short8*)(Ac + s0 * 8) = ra0;
        *(short8*)(Ac + s1 * 8) = ra1;
        *(short8*)(Bc + s0 * 8) = rb0;
        *(short8*)(Bc + s1 * 8) = rb1;
        if (k0 + 32 < 256) {
            ra0 = *(const short8*)(a0p + k0 + 32);
            ra1 = *(const short8*)(a1p + k0 + 32);
            rb0 = *(const short8*)(b0p + k0 + 32);
            rb1 = *(const short8*)(b1p + k0 + 32);
        }
        __syncthreads();
        mfma_tilestep(Ac, Bc, wr, wc, l, acc);
        cur ^= 1;
    }
}

// -------------------- value GEMM tile (fp32 A, staged cvt) ------------------
__device__ __forceinline__ void value_tile(int vbid, int t, const float* __restrict__ src,
        const unsigned short* __restrict__ BT_val, const float* __restrict__ val_b,
        unsigned short* __restrict__ value_bf, unsigned short* Sh) {
    int l = t & 63, w = t >> 6;
    int wr = (w >> 1) * 64, wc = (w & 1) * 64;
    int row0 = (vbid % 831) * 128, col0 = (vbid / 831) * 128;
    f32x4 acc[4][4];
    #pragma unroll
    for (int m = 0; m < 4; ++m)
        #pragma unroll
        for (int n = 0; n < 4; ++n) acc[m][n] = (f32x4){0.f, 0.f, 0.f, 0.f};
    int s0 = t, s1 = t + 256;
    int r0c = min(row0 + (s0 >> 2), MV - 1);
    int r1c = min(row0 + (s1 >> 2), MV - 1);
    const float* a0p = src + (size_t)r0c * 256 + (s0 & 3) * 8;
    const float* a1p = src + (size_t)r1c * 256 + (s1 & 3) * 8;
    const unsigned short* Bg = BT_val + (size_t)col0 * 256;
    const unsigned short* b0p = Bg + (size_t)(s0 >> 2) * 256 + (s0 & 3) * 8;
    const unsigned short* b1p = Bg + (size_t)(s1 >> 2) * 256 + (s1 & 3) * 8;
    float4 fa0 = *(const float4*)(a0p);
    float4 fa1 = *(const float4*)(a0p + 4);
    float4 fb0 = *(const float4*)(a1p);
    float4 fb1 = *(const float4*)(a1p + 4);
    short8 rb0 = *(const short8*)(b0p);
    short8 rb1 = *(const short8*)(b1p);
    int cur = 0;
    for (int k0 = 0; k0 < 256; k0 += 32) {
        unsigned short* Ac = Sh + cur * 4096;
        unsigned short* Bc = Sh + 8192 + cur * 4096;
        short8 ra0, ra1;
        ra0[0] = (short)f2bf(fa0.x); ra0[1] = (short)f2bf(fa0.y);
        ra0[2] = (short)f2bf(fa0.z); ra0[3] = (short)f2bf(fa0.w);
        ra0[4] = (short)f2bf(fa1.x); ra0[5] = (short)f2bf(fa1.y);
        ra0[6] = (short)f2bf(fa1.z); ra0[7] = (short)f2bf(fa1.w);
        ra1[0] = (short)f2bf(fb0.x); ra1[1] = (short)f2bf(fb0.y);
        ra1[2] = (short)f2bf(fb0.z); ra1[3] = (short)f2bf(fb0.w);
        ra1[4] = (short)f2bf(fb1.x); ra1[5] = (short)f2bf(fb1.y);
        ra1[6] = (short)f2bf(fb1.z); ra1[7] = (short)f2bf(fb1.w);
        *(short8*)(Ac + s0 * 8) = ra0;
        *(short8*)(Ac + s1 * 8) = ra1;
        *(short8*)(Bc + s0 * 8) = rb0;
        *(short8*)(Bc + s1 * 8) = rb1;
        if (k0 + 32 < 256) {
            fa0 = *(const float4*)(a0p + k0 + 32);
            fa1 = *(const float4*)(a0p + k0 + 36);
            fb0 = *(const float4*)(a1p + k0 + 32);
            fb1 = *(const float4*)(a1p + k0 + 36);
            rb0 = *(const short8*)(b0p + k0 + 32);
            rb1 = *(const short8*)(b1p + k0 + 32);
        }
        __syncthreads();
        mfma_tilestep(Ac, Bc, wr, wc, l, acc);
        cur ^= 1;
    }
    int cr = (l >> 4) * 4, cc = l & 15;
    #pragma unroll
    for (int m = 0; m < 4; ++m) {
        #pragma unroll
        for (int n = 0; n < 4; ++n) {
            int col = col0 + wc + n * 16 + cc;
            float bv = val_b[col];
            #pragma unroll
            for (int j = 0; j < 4; ++j) {
                int r = row0 + wr + m * 16 + cr + j;
                if (r < MV)
                    value_bf[(size_t)r * 256 + col] = f2bf(acc[m][n][j] + bv);
            }
        }
    }
}

// -------------------- flash attention block (flat sid) ----------------------
__device__ __forceinline__ void flash_block(int sid, int t,
        const unsigned short* __restrict__ qk, const unsigned short* __restrict__ vt,
        unsigned short* __restrict__ out, unsigned short* P_lds /* >= 4608 ushorts */) {
    int l = t & 63, w = t >> 6;
    int lr = l & 15, lg = l >> 4;
    int qt = sid % 15, h = (sid / 15) % 8, b = sid / 120;
    const float scale = 0.17677669529663687f;
    unsigned short* Pw = P_lds + w * 1152;   // [16][72]

    short8 qf = *(const short8*)(qk + (size_t)(b * LQm + qt * 64 + w * 16 + lr) * 512 + h * 32 + lg * 8);

    f32x4 accO[2];
    accO[0] = (f32x4){0.f, 0.f, 0.f, 0.f};
    accO[1] = (f32x4){0.f, 0.f, 0.f, 0.f};
    float mrow[4] = {-1e30f, -1e30f, -1e30f, -1e30f};
    float lrow[4] = {0.f, 0.f, 0.f, 0.f};
    const f32x4 zero = (f32x4){0.f, 0.f, 0.f, 0.f};
    const unsigned short* vtb = vt + ((size_t)(b * 256 + h * 32)) * LQP;

    for (int kt = 0; kt < 15; ++kt) {
        int k0 = kt * 64;
        f32x4 sfr[4];
        #pragma unroll
        for (int ks = 0; ks < 4; ++ks) {
            short8 kf = *(const short8*)(qk + (size_t)(b * LQm + k0 + ks * 16 + lr) * 512 + 256 + h * 32 + lg * 8);
            sfr[ks] = __builtin_amdgcn_mfma_f32_16x16x32_bf16(qf, kf, zero, 0, 0, 0);
        }
        float sv[4][4];
        #pragma unroll
        for (int ks = 0; ks < 4; ++ks) {
            bool valid = (k0 + ks * 16 + lr) < LQm;
            #pragma unroll
            for (int j = 0; j < 4; ++j)
                sv[ks][j] = valid ? sfr[ks][j] * scale : -1e30f;
        }
        float tm[4], newm[4], rr[4], ps[4];
        #pragma unroll
        for (int j = 0; j < 4; ++j)
            tm[j] = fmaxf(fmaxf(sv[0][j], sv[1][j]), fmaxf(sv[2][j], sv[3][j]));
        #pragma unroll
        for (int msk = 1; msk <= 8; msk <<= 1) {
            #pragma unroll
            for (int j = 0; j < 4; ++j) tm[j] = fmaxf(tm[j], __shfl_xor(tm[j], msk));
        }
        #pragma unroll
        for (int j = 0; j < 4; ++j) {
            newm[j] = fmaxf(mrow[j], tm[j]);
            rr[j] = __expf(mrow[j] - newm[j]);
            mrow[j] = newm[j];
            ps[j] = 0.f;
        }
        float pv[4][4];
        #pragma unroll
        for (int ks = 0; ks < 4; ++ks)
            #pragma unroll
            for (int j = 0; j < 4; ++j) {
                pv[ks][j] = __expf(sv[ks][j] - newm[j]);
                ps[j] += pv[ks][j];
            }
        #pragma unroll
        for (int msk = 1; msk <= 8; msk <<= 1) {
            #pragma unroll
            for (int j = 0; j < 4; ++j) ps[j] += __shfl_xor(ps[j], msk);
        }
        #pragma unroll
        for (int j = 0; j < 4; ++j) lrow[j] = lrow[j] * rr[j] + ps[j];
        #pragma unroll
        for (int n = 0; n < 2; ++n)
            #pragma unroll
            for (int j = 0; j < 4; ++j) accO[n][j] *= rr[j];
        #pragma unroll
        for (int ks = 0; ks < 4; ++ks)
            #pragma unroll
            for (int j = 0; j < 4; ++j)
                Pw[(lg * 4 + j) * 72 + ks * 16 + lr] = f2bf(pv[ks][j]);
        #pragma unroll
        for (int kh2 = 0; kh2 < 2; ++kh2) {
            short8 pf = *(const short8*)(Pw + lr * 72 + kh2 * 32 + lg * 8);
            #pragma unroll
            for (int n = 0; n < 2; ++n) {
                short8 vf = *(const short8*)(vtb + (size_t)(n * 16 + lr) * LQP + k0 + kh2 * 32 + lg * 8);
                accO[n] = __builtin_amdgcn_mfma_f32_16x16x32_bf16(pf, vf, accO[n], 0, 0, 0);
            }
        }
    }
    float inv[4];
    #pragma unroll
    for (int j = 0; j < 4; ++j) inv[j] = 1.0f / lrow[j];
    #pragma unroll
    for (int n = 0; n < 2; ++n)
        #pragma unroll
        for (int j = 0; j < 4; ++j) {
            int q = qt * 64 + w * 16 + lg * 4 + j;
            if (q < LQm)
                out[(size_t)(b * LQm + q) * 256 + h * 32 + n * 16 + lr] = f2bf(accO[n][j] * inv[j]);
        }
}

// -------------------- LN (+QP) block ----------------------------------------
__device__ __forceinline__ void ln_block(int sid, int t, const float* __restrict__ x,
        const float* __restrict__ r, const float* __restrict__ w, const float* __restrict__ b,
        const float* __restrict__ qpos, float* __restrict__ out,
        unsigned short* __restrict__ outq) {
    int row = sid * 4 + (t >> 6);
    int lane = t & 63;
    size_t i4 = (size_t)row * 64 + lane;
    float4 xv = reinterpret_cast<const float4*>(x)[i4];
    float4 rv = reinterpret_cast<const float4*>(r)[i4];
    float4 v = make_float4(xv.x + rv.x, xv.y + rv.y, xv.z + rv.z, xv.w + rv.w);
    float s = v.x + v.y + v.z + v.w;
    #pragma unroll
    for (int msk = 1; msk <= 32; msk <<= 1) s += __shfl_xor(s, msk);
    float mean = s * (1.0f / Dm);
    float4 dv = make_float4(v.x - mean, v.y - mean, v.z - mean, v.w - mean);
    float sq = dv.x * dv.x + dv.y * dv.y + dv.z * dv.z + dv.w * dv.w;
    #pragma unroll
    for (int msk = 1; msk <= 32; msk <<= 1) sq += __shfl_xor(sq, msk);
    float is = rsqrtf(sq * (1.0f / Dm) + 1e-5f);
    float4 wv = reinterpret_cast<const float4*>(w)[lane];
    float4 bv = reinterpret_cast<const float4*>(b)[lane];
    float4 res = make_float4(dv.x * is * wv.x + bv.x, dv.y * is * wv.y + bv.y,
                             dv.z * is * wv.z + bv.z, dv.w * is * wv.w + bv.w);
    reinterpret_cast<float4*>(out)[i4] = res;
    float4 qv = reinterpret_cast<const float4*>(qpos)[i4];
    ushort4 u;
    u.x = f2bf(res.x + qv.x); u.y = f2bf(res.y + qv.y);
    u.z = f2bf(res.z + qv.z); u.w = f2bf(res.w + qv.w);
    reinterpret_cast<ushort4*>(outq)[i4] = u;
}

// -------------------- combo kernels: value chunk + chain branch -------------
// SEC 0: qkh(228)+Vt(114)+vtpad(480); SEC 1: flash(960); SEC 2: sa(114);
// SEC 3: LN2+QP(1800); SEC 4: offaw(171)
template <int SEC>
__global__ __launch_bounds__(256) void combo(int vlo, int vcnt,
        const float* __restrict__ src, const unsigned short* __restrict__ BT_val,
        const float* __restrict__ val_b, unsigned short* __restrict__ value_bf,
        const unsigned short* __restrict__ Qbf, const unsigned short* __restrict__ BT_qkv,
        const float* __restrict__ qkv_b, unsigned short* __restrict__ qk_bf,
        const unsigned short* __restrict__ tgt_bf, unsigned short* __restrict__ Vt,
        const unsigned short* __restrict__ attn_bf, const unsigned short* __restrict__ BT_out,
        const float* __restrict__ out_b, float* __restrict__ S1,
        const float* __restrict__ tgt, const float* __restrict__ qpos,
        const float* __restrict__ ln2_w, const float* __restrict__ ln2_b,
        float* __restrict__ t1, unsigned short* __restrict__ Qbf_out,
        const unsigned short* __restrict__ BT_off, const float* __restrict__ off_b,
        const float* __restrict__ aw_b, float* __restrict__ offb, float* __restrict__ awb,
        unsigned short* __restrict__ attn_out) {
    __shared__ __align__(16) unsigned short Sh[16384];   // 32 KB
    int bid = blockIdx.x;
    int t = threadIdx.x;
    if (bid < vcnt) {
        value_tile(vlo + bid, t, src, BT_val, val_b, value_bf, Sh);
        return;
    }
    int sid = bid - vcnt;
    int l = t & 63, w = t >> 6;
    int wr = (w >> 1) * 64, wc = (w & 1) * 64;
    int cr = ((l >> 4)) * 4, cc = l & 15;

    if (SEC == 0) {
        if (sid < 342) {
            bool is_qk = (sid < 228);
            int idx = is_qk ? sid : (sid - 228);
            int row0 = (idx % 57) * 128, col0 = (idx / 57) * 128;
            const unsigned short* A  = is_qk ? Qbf : tgt_bf;
            const unsigned short* BT = is_qk ? BT_qkv : (BT_qkv + 512 * 256);
            const float* bias        = is_qk ? qkv_b : (qkv_b + 512);
            f32x4 acc[4][4];
            #pragma unroll
            for (int m = 0; m < 4; ++m)
                #pragma unroll
                for (int n = 0; n < 4; ++n) acc[m][n] = (f32x4){0.f, 0.f, 0.f, 0.f};
            bf16_mainloop(t, A + (size_t)row0 * 256, BT + (size_t)col0 * 256, Sh, acc);
            if (is_qk) {
                #pragma unroll
                for (int m = 0; m < 4; ++m)
                    #pragma unroll
                    for (int n = 0; n < 4; ++n) {
                        int col = col0 + wc + n * 16 + cc;
                        float bv = bias[col];
                        #pragma unroll
                        for (int j = 0; j < 4; ++j) {
                            int r = row0 + wr + m * 16 + cr + j;
                            if (r < MQ)
                                qk_bf[(size_t)r * 512 + col] = f2bf(acc[m][n][j] + bv);
                        }
                    }
            } else {
                #pragma unroll
                for (int m = 0; m < 4; ++m)
                    #pragma unroll
                    for (int n = 0; n < 4; ++n) {
                        int col = col0 + wc + n * 16 + cc;
                        float bv = bias[col];
                        int r0 = row0 + wr + m * 16 + cr;
                        if (r0 < MQ) {
                            int bb = r0 / 900;
                            int q = r0 - bb * 900;
                            ushort4 u;
                            u.x = f2bf(acc[m][n][0] + bv);
                            u.y = f2bf(acc[m][n][1] + bv);
                            u.z = f2bf(acc[m][n][2] + bv);
                            u.w = f2bf(acc[m][n][3] + bv);
                            *reinterpret_cast<ushort4*>(Vt + ((size_t)(bb * 256 + col)) * LQP + q) = u;
                        }
                    }
            }
        } else {
            int i = (sid - 342) * 256 + t;       // 480*256: vtpad
            int row = i / 60, c = 900 + (i % 60);
            Vt[(size_t)row * LQP + c] = 0;
        }
    } else if (SEC == 1) {
        flash_block(sid, t, qk_bf, Vt, attn_out, Sh);
    } else if (SEC == 2) {
        int row0 = (sid % 57) * 128, col0 = (sid / 57) * 128;
        f32x4 acc[4][4];
        #pragma unroll
        for (int m = 0; m < 4; ++m)
            #pragma unroll
            for (int n = 0; n < 4; ++n) acc[m][n] = (f32x4){0.f, 0.f, 0.f, 0.f};
        bf16_mainloop(t, attn_bf + (size_t)row0 * 256, BT_out + (size_t)col0 * 256, Sh, acc);
        #pragma unroll
        for (int m = 0; m < 4; ++m)
            #pragma unroll
            for (int n = 0; n < 4; ++n) {
                int col = col0 + wc + n * 16 + cc;
                float bv = out_b[col];
                #pragma unroll
                for (int j = 0; j < 4; ++j) {
                    int r = row0 + wr + m * 16 + cr + j;
                    if (r < MQ)
                        S1[(size_t)r * 256 + col] = acc[m][n][j] + bv;
                }
            }
    } else if (SEC == 3) {
        ln_block(sid, t, tgt, S1, ln2_w, ln2_b, qpos, t1, Qbf_out);
    } else {   // SEC == 4: fused off+aw, N=384
        int row0 = (sid % 57) * 128, col0 = (sid / 57) * 128;
        f32x4 acc[4][4];
        #pragma unroll
        for (int m = 0; m < 4; ++m)
            #pragma unroll
            for (int n = 0; n < 4; ++n) acc[m][n] = (f32x4){0.f, 0.f, 0.f, 0.f};
        bf16_mainloop(t, Qbf + (size_t)row0 * 256, BT_off + (size_t)col0 * 256, Sh, acc);
        #pragma unroll
        for (int m = 0; m < 4; ++m)
            #pragma unroll
            for (int n = 0; n < 4; ++n) {
                int col = col0 + wc + n * 16 + cc;
                float bv = (col < 256) ? off_b[col] : aw_b[col - 256];
                #pragma unroll
                for (int j = 0; j < 4; ++j) {
                    int r = row0 + wr + m * 16 + cr + j;
                    if (r < MQ) {
                        float v = acc[m][n][j] + bv;
                        if (col < 256) offb[(size_t)r * 256 + col] = v;
                        else           awb[(size_t)r * 128 + (col - 256)] = v;
                    }
                }
            }
    }
}

// -------------------- bf16 MFMA GEMM (tail: op/ffn/ff) ----------------------
template <int RELU, int OBF>
__global__ __launch_bounds__(256) void bgemm(int M, int N, int K,
        const unsigned short* __restrict__ A,
        const unsigned short* __restrict__ BT,
        const float* __restrict__ bias,
        float* __restrict__ Cf, unsigned short* __restrict__ Cb, int ldc) {
    __shared__ __align__(16) unsigned short As[2][128 * 32];
    __shared__ __align__(16) unsigned short Bs[2][128 * 32];
    int t = threadIdx.x;
    int l = t & 63;
    int w = t >> 6;
    int row0 = blockIdx.x * 128, col0 = blockIdx.y * 128;
    int wr = (w >> 1) * 64, wc = (w & 1) * 64;
    f32x4 acc[4][4];
    #pragma unroll
    for (int m = 0; m < 4; ++m)
        #pragma unroll
        for (int n = 0; n < 4; ++n) acc[m][n] = (f32x4){0.f, 0.f, 0.f, 0.f};

    int s0 = t, s1 = t + 256;
    const unsigned short* Ag = A + (size_t)row0 * K;
    const unsigned short* Bg = BT + (size_t)col0 * K;
    const unsigned short* a0p = Ag + (size_t)(s0 >> 2) * K + (s0 & 3) * 8;
    const unsigned short* a1p = Ag + (size_t)(s1 >> 2) * K + (s1 & 3) * 8;
    const unsigned short* b0p = Bg + (size_t)(s0 >> 2) * K + (s0 & 3) * 8;
    const unsigned short* b1p = Bg + (size_t)(s1 >> 2) * K + (s1 & 3) * 8;

    short8 ra0 = *(const short8*)(a0p);
    short8 ra1 = *(const short8*)(a1p);
    short8 rb0 = *(const short8*)(b0p);
    short8 rb1 = *(const short8*)(b1p);

    int cur = 0;
    for (int k0 = 0; k0 < K; k0 += 32) {
        unsigned short* Ac = As[cur];
        unsigned short* Bc = Bs[cur];
        *(short8*)(Ac + s0 * 8) = ra0;
        *(short8*)(Ac + s1 * 8) = ra1;
        *(short8*)(Bc + s0 * 8) = rb0;
        *(short8*)(Bc + s1 * 8) = rb1;
        if (k0 + 32 < K) {
            ra0 = *(const short8*)(a0p + k0 + 32);
            ra1 = *(const short8*)(a1p + k0 + 32);
            rb0 = *(const short8*)(b0p + k0 + 32);
            rb1 = *(const short8*)(b1p + k0 + 32);
        }
        __syncthreads();
        mfma_tilestep(Ac, Bc, wr, wc, l, acc);
        cur ^= 1;
    }

    int cr = (l >> 4) * 4;
    int cc = l & 15;
    #pragma unroll
    for (int m = 0; m < 4; ++m) {
        #pragma unroll
        for (int n = 0; n < 4; ++n) {
            int col = col0 + wc + n * 16 + cc;
            float bv = bias[col];
            #pragma unroll
            for (int j = 0; j < 4; ++j) {
                int r = row0 + wr + m * 16 + cr + j;
                if (r < M) {
                    float v = acc[m][n][j] + bv;
                    if (RELU) v = fmaxf(v, 0.f);
                    if (OBF) Cb[(size_t)r * ldc + col] = f2bf(v);
                    else     Cf[(size_t)r * ldc + col] = v;
                }
            }
        }
    }
}

// -------------------- residual add + LayerNorm (LN1 / LN3) ------------------
template <int DUAL>
__global__ __launch_bounds__(256) void add_ln_kernel(const float* __restrict__ x,
                                                     const float* __restrict__ r,
                                                     const float* __restrict__ w,
                                                     const float* __restrict__ b,
                                                     float* __restrict__ out,
                                                     unsigned short* __restrict__ outb) {
    int row = blockIdx.x * 4 + (threadIdx.x >> 6);
    int lane = threadIdx.x & 63;
    size_t i4 = (size_t)row * 64 + lane;
    float4 xv = reinterpret_cast<const float4*>(x)[i4];
    float4 rv = reinterpret_cast<const float4*>(r)[i4];
    float4 v = make_float4(xv.x + rv.x, xv.y + rv.y, xv.z + rv.z, xv.w + rv.w);
    float s = v.x + v.y + v.z + v.w;
    #pragma unroll
    for (int msk = 1; msk <= 32; msk <<= 1) s += __shfl_xor(s, msk);
    float mean = s * (1.0f / Dm);
    float4 dv = make_float4(v.x - mean, v.y - mean, v.z - mean, v.w - mean);
    float sq = dv.x * dv.x + dv.y * dv.y + dv.z * dv.z + dv.w * dv.w;
    #pragma unroll
    for (int msk = 1; msk <= 32; msk <<= 1) sq += __shfl_xor(sq, msk);
    float is = rsqrtf(sq * (1.0f / Dm) + 1e-5f);
    float4 wv = reinterpret_cast<const float4*>(w)[lane];
    float4 bv = reinterpret_cast<const float4*>(b)[lane];
    float4 res = make_float4(dv.x * is * wv.x + bv.x, dv.y * is * wv.y + bv.y,
                             dv.z * is * wv.z + bv.z, dv.w * is * wv.w + bv.w);
    reinterpret_cast<float4*>(out)[i4] = res;
    if (DUAL) {
        ushort4 u;
        u.x = f2bf(res.x); u.y = f2bf(res.y); u.z = f2bf(res.z); u.w = f2bf(res.w);
        reinterpret_cast<ushort4*>(outb)[i4] = u;
    }
}

// -------------------- ms-deformable sampling: wave per query ----------------
__global__ __launch_bounds__(256) void msdeform_kernel(const unsigned short* __restrict__ value,
                                                       const float* __restrict__ ref,
                                                       const float* __restrict__ off,
                                                       const float* __restrict__ awl,
                                                       unsigned short* __restrict__ out) {
    const int HL[4] = {100, 50, 25, 13};
    const int ST[4] = {0, 10000, 12500, 13125};
    __shared__ float lsx[4][128], lsy[4][128], wtab[4][128];
    __shared__ float2 ctab[4][512];
    int wv = threadIdx.x >> 6, lane = threadIdx.x & 63;
    int m = blockIdx.x * 4 + wv;
    int b = m / LQm;

    #pragma unroll
    for (int e = lane; e < 128; e += 64) {
        int lev = (e >> 2) & 3;
        float rx = ref[((size_t)m * NLEVm + lev) * 2 + 0];
        float ry = ref[((size_t)m * NLEVm + lev) * 2 + 1];
        float ox = off[(size_t)m * 256 + e * 2 + 0];
        float oy = off[(size_t)m * 256 + e * 2 + 1];
        float Wf = (float)HL[lev];
        lsx[wv][e] = (rx + ox / Wf) * Wf - 0.5f;
        lsy[wv][e] = (ry + oy / Wf) * Wf - 0.5f;
        wtab[wv][e] = awl[(size_t)m * 128 + e];
    }
    __syncthreads();
    if (lane < NHm) {
        int h = lane;
        float mx = -1e30f;
        #pragma unroll
        for (int i = 0; i < 16; i++) mx = fmaxf(mx, wtab[wv][h * 16 + i]);
        float s = 0.f;
        #pragma unroll
        for (int i = 0; i < 16; i++) {
            float e = __expf(wtab[wv][h * 16 + i] - mx);
            wtab[wv][h * 16 + i] = e; s += e;
        }
        float inv = 1.0f / s;
        #pragma unroll
        for (int i = 0; i < 16; i++) wtab[wv][h * 16 + i] *= inv;
    }
    __syncthreads();
    #pragma unroll
    for (int j = 0; j < 8; ++j) {
        int e2 = lane * 8 + j;
        int c = e2 & 3, e = e2 >> 2;
        int lev = (e >> 2) & 3;
        int Wl = HL[lev];
        float lx = lsx[wv][e], ly = lsy[wv][e];
        float x0f = floorf(lx), y0f = floorf(ly);
        float fx = lx - x0f, fy = ly - y0f;
        int dx = c & 1, dy = c >> 1;
        int xi = (int)x0f + dx, yi = (int)y0f + dy;
        bool valid = (xi >= 0) && (xi < Wl) && (yi >= 0) && (yi < Wl);
        float wc = valid ? ((dx ? fx : 1.0f - fx) * (dy ? fy : 1.0f - fy)) * wtab[wv][e] : 0.f;
        int xc = min(max(xi, 0), Wl - 1), yc = min(max(yi, 0), Wl - 1);
        int row = b * LENm + ST[lev] + yc * Wl + xc;
        ctab[wv][e2] = make_float2(__int_as_float(row), wc);
    }
    __syncthreads();
    int h = lane >> 3, dg = lane & 7;
    const unsigned short* basep = value + h * 32 + dg * 4;
    float a0 = 0.f, a1 = 0.f, a2 = 0.f, a3 = 0.f;
    #pragma unroll
    for (int i = 0; i < 16; ++i) {
        #pragma unroll
        for (int c = 0; c < 4; ++c) {
            float2 cc = ctab[wv][(h * 16 + i) * 4 + c];
            int row = __float_as_int(cc.x);
            float wc = cc.y;
            ushort4 v = *reinterpret_cast<const ushort4*>(basep + (size_t)row * 256);
            a0 += wc * bf2f(v.x); a1 += wc * bf2f(v.y);
            a2 += wc * bf2f(v.z); a3 += wc * bf2f(v.w);
        }
    }
    ushort4 o;
    o.x = f2bf(a0); o.y = f2bf(a1); o.z = f2bf(a2); o.w = f2bf(a3);
    *reinterpret_cast<ushort4*>(out + (size_t)m * 256 + h * 32 + dg * 4) = o;
}

// ------------------------------------------------------------------
extern "C" void kernel_launch(void* const* d_in, const int* in_sizes, int n_in,
                              void* d_out, int out_size, void* d_ws, size_t ws_size,
                              hipStream_t stream) {
    const float* tgt   = (const float*)d_in[0];
    const float* qpos  = (const float*)d_in[1];
    const float* refp  = (const float*)d_in[2];
    const float* src   = (const float*)d_in[3];
    const float* qkv_w = (const float*)d_in[6];
    const float* qkv_b = (const float*)d_in[7];
    const float* out_w = (const float*)d_in[8];
    const float* out_b = (const float*)d_in[9];
    const float* ln2_w = (const float*)d_in[10];
    const float* ln2_b = (const float*)d_in[11];
    const float* val_w = (const float*)d_in[12];
    const float* val_b = (const float*)d_in[13];
    const float* off_w = (const float*)d_in[14];
    const float* off_b = (const float*)d_in[15];
    const float* aw_w  = (const float*)d_in[16];
    const float* aw_b  = (const float*)d_in[17];
    const float* op_w  = (const float*)d_in[18];
    const float* op_b  = (const float*)d_in[19];
    const float* ln1_w = (const float*)d_in[20];
    const float* ln1_b = (const float*)d_in[21];
    const float* w1    = (const float*)d_in[22];
    const float* b1    = (const float*)d_in[23];
    const float* w2    = (const float*)d_in[24];
    const float* b2    = (const float*)d_in[25];
    const float* ln3_w = (const float*)d_in[26];
    const float* ln3_b = (const float*)d_in[27];

    char* base = (char*)d_ws;
    unsigned short* value_bf  = (unsigned short*)(base);                      // 54,460,416
    unsigned short* hidden_bf = (unsigned short*)(base + 54460416);
    unsigned short* t2_bf     = (unsigned short*)(base + 54460416 + 14942208);
    unsigned short* qk_bf = (unsigned short*)(base + 108920832);
    float* offb = (float*)(base + 108920832);                                 // aliases qk_bf (after flash)
    float* awb  = (float*)(base + 108920832 + 7372800);
    unsigned short* Vt = (unsigned short*)(base + 123666432);
    float* S1   = (float*)(base + 123666432);                                 // aliases Vt (after flash)
    float* t1   = (float*)(base + 131039232);
    float* t2   = (float*)(base + 138412032);
    unsigned short* Qbf     = (unsigned short*)(base + 145784832);
    unsigned short* tgt_bf  = (unsigned short*)(base + 149520384);
    unsigned short* attn_bf = (unsigned short*)(base + 153255936);
    unsigned short* ca_bf   = (unsigned short*)(base + 156991488);
    unsigned short* BT_qkv  = (unsigned short*)(base + 160727040);
    unsigned short* BT_out  = BT_qkv + 768 * 256;
    unsigned short* BT_val  = BT_out + 256 * 256;
    unsigned short* BT_off  = BT_val + 256 * 256;
    unsigned short* BT_aw   = BT_off + 256 * 256;                             // contiguous after BT_off
    unsigned short* BT_op   = BT_aw + 128 * 256;
    unsigned short* BT_w1   = BT_op + 256 * 256;
    unsigned short* BT_w2   = BT_w1 + 1024 * 256;
    float* outp = (float*)d_out;

    dim3 blk(256);
    // L1: weight transposes + prep (248 + 1824 blocks)
    wt_prep<<<dim3(2072), blk, 0, stream>>>(qkv_w, out_w, val_w, off_w, aw_w, op_w, w1, w2,
                                            BT_qkv, BT_out, BT_val, BT_off, BT_aw, BT_op, BT_w1, BT_w2,
                                            tgt, qpos, tgt_bf, Qbf);

    #define COMBO_ARGS src, BT_val, val_b, value_bf, Qbf, BT_qkv, qkv_b, qk_bf, tgt_bf, Vt, \
                       attn_bf, BT_out, out_b, S1, tgt, qpos, ln2_w, ln2_b, t1, Qbf, \
                       BT_off, off_b, aw_b, offb, awb, attn_bf
    // L2: value[0,333) + qkh + Vt + vtpad
    combo<0><<<dim3(333 + 822), blk, 0, stream>>>(0, 333, COMBO_ARGS);
    // L3: value[333,999) + flash
    combo<1><<<dim3(666 + 960), blk, 0, stream>>>(333, 666, COMBO_ARGS);
    // L4: value[999,1331) + sa proj
    combo<2><<<dim3(332 + 114), blk, 0, stream>>>(999, 332, COMBO_ARGS);
    // L5: value[1331,1497) + LN2(+qpos -> Qbf)
    combo<3><<<dim3(166 + 1800), blk, 0, stream>>>(1331, 166, COMBO_ARGS);
    // L6: value[1497,1662) + off/aw proj
    combo<4><<<dim3(165 + 171), blk, 0, stream>>>(1497, 165, COMBO_ARGS);
    #undef COMBO_ARGS

    // L7: msdeform -> ca_bf
    msdeform_kernel<<<dim3(1800), blk, 0, stream>>>(value_bf, refp, offb, awb, ca_bf);
    // L8: op proj -> S1
    bgemm<0, 0><<<dim3(57, 2), blk, 0, stream>>>(MQ, 256, 256, ca_bf, BT_op, op_b, S1, nullptr, 256);
    // L9: t2 = LN(t1 + ca; ln1) -> t2 + t2_bf
    add_ln_kernel<1><<<dim3(1800), blk, 0, stream>>>(t1, S1, ln1_w, ln1_b, t2, t2_bf);
    // L10: ffn hidden
    bgemm<1, 1><<<dim3(57, 8), blk, 0, stream>>>(MQ, DFFNm, 256, t2_bf, BT_w1, b1, nullptr, hidden_bf, DFFNm);
    // L11: ff
    bgemm<0, 0><<<dim3(57, 2), blk, 0, stream>>>(MQ, 256, 1024, hidden_bf, BT_w2, b2, S1, nullptr, 256);
    // L12: out = LN(t2 + ff; ln3)
    add_ln_kernel<0><<<dim3(1800), blk, 0, stream>>>(t2, S1, ln3_w, ln3_b, outp, nullptr);
}

// Round 14
// 243.062 us; speedup vs baseline: 1.0684x; 1.0684x over previous
//
#include <hip/hip_runtime.h>
#include <math.h>

#define Dm    256
#define NHm   8
#define DHm   32
#define NLEVm 4
#define NPTSm 4
#define DFFNm 1024
#define Bm    8
#define LQm   900
#define LENm  13294
#define MQ    (Bm * LQm)      // 7200
#define MV    (Bm * LENm)     // 106352
#define MQP   7296            // MQ padded to 128
#define MVP   106368          // MV padded to 128
#define LQP   960             // keys padded to 15*64

typedef __attribute__((ext_vector_type(8))) short short8;   // 8 bf16 (4 VGPRs)
typedef __attribute__((ext_vector_type(4))) float f32x4;    // MFMA acc

__device__ __forceinline__ unsigned short f2bf(float f) {
    unsigned int b = __float_as_uint(f);
    unsigned int r = (b + 0x7FFFu + ((b >> 16) & 1u)) >> 16;
    return (unsigned short)r;
}
__device__ __forceinline__ float bf2f(unsigned short u) {
    return __uint_as_float(((unsigned int)u) << 16);
}

// -------------------- fused weight transposes + prep (one launch) -----------
__device__ __forceinline__ void wt_tile(const float* __restrict__ W,
                                        unsigned short* __restrict__ BT,
                                        int N, int K, int n0, int k0, int t,
                                        float (*tile)[65]) {
    #pragma unroll
    for (int r0 = 0; r0 < 64; r0 += 16) {
        int r = r0 + (t >> 4);
        int c = (t & 15) * 4;
        float4 v = *reinterpret_cast<const float4*>(W + (size_t)(k0 + r) * N + n0 + c);
        tile[r][c + 0] = v.x; tile[r][c + 1] = v.y; tile[r][c + 2] = v.z; tile[r][c + 3] = v.w;
    }
    __syncthreads();
    #pragma unroll
    for (int s = t; s < 512; s += 256) {
        int r = s >> 3, c8 = (s & 7) * 8;
        short8 u;
        #pragma unroll
        for (int j = 0; j < 8; ++j) u[j] = (short)f2bf(tile[c8 + j][r]);
        *reinterpret_cast<short8*>(BT + (size_t)(n0 + r) * K + k0 + c8) = u;
    }
}

__global__ __launch_bounds__(256) void wt_prep(
        const float* __restrict__ qkv_w, const float* __restrict__ out_w,
        const float* __restrict__ val_w, const float* __restrict__ off_w,
        const float* __restrict__ aw_w,  const float* __restrict__ op_w,
        const float* __restrict__ w1,    const float* __restrict__ w2,
        unsigned short* __restrict__ BT_qkv, unsigned short* __restrict__ BT_out,
        unsigned short* __restrict__ BT_val, unsigned short* __restrict__ BT_off,
        unsigned short* __restrict__ BT_aw,  unsigned short* __restrict__ BT_op,
        unsigned short* __restrict__ BT_w1,  unsigned short* __restrict__ BT_w2,
        const float* __restrict__ tgt, const float* __restrict__ qpos,
        unsigned short* __restrict__ tgtb, unsigned short* __restrict__ qb) {
    __shared__ float tile[64][65];
    int bid = blockIdx.x;
    int t = threadIdx.x;
    if (bid >= 248) {                        // prep: tgt_bf + Qbf
        int i = (bid - 248) * 256 + t;       // < 466944 = MQP*64
        ushort4 ut, uq;
        if (i < MQ * 64) {
            float4 x = reinterpret_cast<const float4*>(tgt)[i];
            float4 y = reinterpret_cast<const float4*>(qpos)[i];
            ut.x = f2bf(x.x); ut.y = f2bf(x.y); ut.z = f2bf(x.z); ut.w = f2bf(x.w);
            uq.x = f2bf(x.x + y.x); uq.y = f2bf(x.y + y.y);
            uq.z = f2bf(x.z + y.z); uq.w = f2bf(x.w + y.w);
        } else {
            ut.x = ut.y = ut.z = ut.w = 0;
            uq.x = uq.y = uq.z = uq.w = 0;
        }
        reinterpret_cast<ushort4*>(tgtb)[i] = ut;
        reinterpret_cast<ushort4*>(qb)[i] = uq;
        return;
    }
    const float* W; unsigned short* BT; int N, K, idx;
    if      (bid < 48)  { W = qkv_w; BT = BT_qkv; N = 768;  K = 256;  idx = bid; }
    else if (bid < 64)  { W = out_w; BT = BT_out; N = 256;  K = 256;  idx = bid - 48; }
    else if (bid < 80)  { W = val_w; BT = BT_val; N = 256;  K = 256;  idx = bid - 64; }
    else if (bid < 96)  { W = off_w; BT = BT_off; N = 256;  K = 256;  idx = bid - 80; }
    else if (bid < 104) { W = aw_w;  BT = BT_aw;  N = 128;  K = 256;  idx = bid - 96; }
    else if (bid < 120) { W = op_w;  BT = BT_op;  N = 256;  K = 256;  idx = bid - 104; }
    else if (bid < 184) { W = w1;    BT = BT_w1;  N = 1024; K = 256;  idx = bid - 120; }
    else                { W = w2;    BT = BT_w2;  N = 256;  K = 1024; idx = bid - 184; }
    int nt = N / 64;
    int n0 = (idx % nt) * 64, k0 = (idx / nt) * 64;
    wt_tile(W, BT, N, K, n0, k0, t, tile);
}

// -------------------- 4x4 MFMA tile step (128-wide tiles, tail GEMMs) -------
__device__ __forceinline__ void mfma_tilestep(const unsigned short* Ac, const unsigned short* Bc,
                                              int wr, int wc, int l, f32x4 acc[4][4]) {
    short8 af[4], bfr[4];
    #pragma unroll
    for (int m = 0; m < 4; ++m)
        af[m] = *(const short8*)(Ac + (wr + m * 16 + (l & 15)) * 32 + (l >> 4) * 8);
    #pragma unroll
    for (int n = 0; n < 4; ++n)
        bfr[n] = *(const short8*)(Bc + (wc + n * 16 + (l & 15)) * 32 + (l >> 4) * 8);
    #pragma unroll
    for (int m = 0; m < 4; ++m)
        #pragma unroll
        for (int n = 0; n < 4; ++n)
            acc[m][n] = __builtin_amdgcn_mfma_f32_16x16x32_bf16(af[m], bfr[n], acc[m][n], 0, 0, 0);
}

// -------------------- 64x128 single-buffer GEMM helpers (fused launch) ------
// LDS: As 2048 ushorts (4KB) + Bs 4096 ushorts (8KB) = 12KB. acc[2][4].
__device__ __forceinline__ void gemm64_core(int t, unsigned short* Sh,
                                            short8& ra, short8& rb0, short8& rb1,
                                            const unsigned short* ap,
                                            const unsigned short* b0p, const unsigned short* b1p,
                                            const float* afp, f32x4 acc[2][4]) {
    int l = t & 63;
    int lr = l & 15, lg = l >> 4;
    int w = t >> 6;
    int wr = (w >> 1) * 32, wc = (w & 1) * 64;
    unsigned short* As = Sh;
    unsigned short* Bs = Sh + 2048;
    for (int k0 = 0; k0 < 256; k0 += 32) {
        __syncthreads();                     // previous compute done
        *(short8*)(As + t * 8) = ra;
        *(short8*)(Bs + t * 8) = rb0;
        *(short8*)(Bs + (t + 256) * 8) = rb1;
        __syncthreads();                     // tile ready
        if (k0 + 32 < 256) {
            if (afp) {
                float4 f0 = *(const float4*)(afp + k0 + 32);
                float4 f1 = *(const float4*)(afp + k0 + 36);
                ra[0] = (short)f2bf(f0.x); ra[1] = (short)f2bf(f0.y);
                ra[2] = (short)f2bf(f0.z); ra[3] = (short)f2bf(f0.w);
                ra[4] = (short)f2bf(f1.x); ra[5] = (short)f2bf(f1.y);
                ra[6] = (short)f2bf(f1.z); ra[7] = (short)f2bf(f1.w);
            } else {
                ra = *(const short8*)(ap + k0 + 32);
            }
            rb0 = *(const short8*)(b0p + k0 + 32);
            rb1 = *(const short8*)(b1p + k0 + 32);
        }
        short8 af[2], bfr[4];
        #pragma unroll
        for (int m = 0; m < 2; ++m)
            af[m] = *(const short8*)(As + (wr + m * 16 + lr) * 32 + lg * 8);
        #pragma unroll
        for (int n = 0; n < 4; ++n)
            bfr[n] = *(const short8*)(Bs + (wc + n * 16 + lr) * 32 + lg * 8);
        #pragma unroll
        for (int m = 0; m < 2; ++m)
            #pragma unroll
            for (int n = 0; n < 4; ++n)
                acc[m][n] = __builtin_amdgcn_mfma_f32_16x16x32_bf16(af[m], bfr[n], acc[m][n], 0, 0, 0);
    }
}

// -------------------- mega-fused launch: value + qkh + Vt + vtpad -----------
// 64x128 tiles everywhere. blocks: [0,3324) value; [3324,3780) qkh;
// [3780,4008) Vt; [4008,4488) vtpad.
__global__ __launch_bounds__(256) void fused_gemms(
        const float* __restrict__ src, const unsigned short* __restrict__ BT_val,
        const float* __restrict__ val_b, unsigned short* __restrict__ value_bf,
        const unsigned short* __restrict__ Qbf, const unsigned short* __restrict__ BT_qkv,
        const float* __restrict__ qkv_b, unsigned short* __restrict__ qk_bf,
        const unsigned short* __restrict__ tgt_bf, unsigned short* __restrict__ Vt) {
    __shared__ __align__(16) unsigned short Sh[6144];    // 12 KB
    int bid = blockIdx.x;
    int t = threadIdx.x;

    if (bid >= 4008) {                       // vtpad
        int i = (bid - 4008) * 256 + t;      // 480*256 = 122880 = 2048*60
        int row = i / 60, c = 900 + (i % 60);
        Vt[(size_t)row * LQP + c] = 0;
        return;
    }

    int l = t & 63, w = t >> 6;
    int lr = l & 15, lg = l >> 4;
    int wr = (w >> 1) * 32, wc = (w & 1) * 64;
    int cr = lg * 4, cc = lr;
    f32x4 acc[2][4];
    #pragma unroll
    for (int m = 0; m < 2; ++m)
        #pragma unroll
        for (int n = 0; n < 4; ++n) acc[m][n] = (f32x4){0.f, 0.f, 0.f, 0.f};

    if (bid < 3324) {
        // ---- value: M=MV (1662 row-tiles of 64), N=256 (2 col-tiles) ----
        int row0 = (bid % 1662) * 64, col0 = (bid / 1662) * 128;
        int rA = min(row0 + (t >> 2), MV - 1);           // clamp: src unpadded
        const float* afp = src + (size_t)rA * 256 + (t & 3) * 8;
        const unsigned short* Bg = BT_val + (size_t)col0 * 256;
        const unsigned short* b0p = Bg + (size_t)(t >> 2) * 256 + (t & 3) * 8;
        const unsigned short* b1p = Bg + (size_t)((t + 256) >> 2) * 256 + ((t + 256) & 3) * 8;
        short8 ra, rb0, rb1;
        {
            float4 f0 = *(const float4*)(afp);
            float4 f1 = *(const float4*)(afp + 4);
            ra[0] = (short)f2bf(f0.x); ra[1] = (short)f2bf(f0.y);
            ra[2] = (short)f2bf(f0.z); ra[3] = (short)f2bf(f0.w);
            ra[4] = (short)f2bf(f1.x); ra[5] = (short)f2bf(f1.y);
            ra[6] = (short)f2bf(f1.z); ra[7] = (short)f2bf(f1.w);
        }
        rb0 = *(const short8*)(b0p);
        rb1 = *(const short8*)(b1p);
        gemm64_core(t, Sh, ra, rb0, rb1, nullptr, b0p, b1p, afp, acc);
        #pragma unroll
        for (int m = 0; m < 2; ++m)
            #pragma unroll
            for (int n = 0; n < 4; ++n) {
                int col = col0 + wc + n * 16 + cc;
                float bv = val_b[col];
                #pragma unroll
                for (int j = 0; j < 4; ++j) {
                    int r = row0 + wr + m * 16 + cr + j;
                    if (r < MV)
                        value_bf[(size_t)r * 256 + col] = f2bf(acc[m][n][j] + bv);
                }
            }
    } else {
        // ---- qkh [3324,3780) or Vt [3780,4008): bf16 A ----
        bool is_qk = (bid < 3780);
        int idx = is_qk ? (bid - 3324) : (bid - 3780);
        int row0 = (idx % 114) * 64;
        int col0 = (idx / 114) * 128;
        const unsigned short* A  = is_qk ? Qbf : tgt_bf;
        const unsigned short* BT = is_qk ? BT_qkv : (BT_qkv + 512 * 256);
        const float* bias        = is_qk ? qkv_b : (qkv_b + 512);
        const unsigned short* ap  = A  + (size_t)(row0 + (t >> 2)) * 256 + (t & 3) * 8;
        const unsigned short* Bg  = BT + (size_t)col0 * 256;
        const unsigned short* b0p = Bg + (size_t)(t >> 2) * 256 + (t & 3) * 8;
        const unsigned short* b1p = Bg + (size_t)((t + 256) >> 2) * 256 + ((t + 256) & 3) * 8;
        short8 ra = *(const short8*)(ap);
        short8 rb0 = *(const short8*)(b0p);
        short8 rb1 = *(const short8*)(b1p);
        gemm64_core(t, Sh, ra, rb0, rb1, ap, b0p, b1p, nullptr, acc);
        if (is_qk) {
            #pragma unroll
            for (int m = 0; m < 2; ++m)
                #pragma unroll
                for (int n = 0; n < 4; ++n) {
                    int col = col0 + wc + n * 16 + cc;
                    float bv = bias[col];
                    #pragma unroll
                    for (int j = 0; j < 4; ++j) {
                        int r = row0 + wr + m * 16 + cr + j;
                        if (r < MQ)
                            qk_bf[(size_t)r * 512 + col] = f2bf(acc[m][n][j] + bv);
                    }
                }
        } else {
            #pragma unroll
            for (int m = 0; m < 2; ++m)
                #pragma unroll
                for (int n = 0; n < 4; ++n) {
                    int col = col0 + wc + n * 16 + cc;
                    float bv = bias[col];
                    int r0 = row0 + wr + m * 16 + cr;    // multiple of 4; 900%4==0
                    if (r0 < MQ) {
                        int bb = r0 / 900;
                        int q = r0 - bb * 900;
                        ushort4 u;
                        u.x = f2bf(acc[m][n][0] + bv);
                        u.y = f2bf(acc[m][n][1] + bv);
                        u.z = f2bf(acc[m][n][2] + bv);
                        u.w = f2bf(acc[m][n][3] + bv);
                        *reinterpret_cast<ushort4*>(Vt + ((size_t)(bb * 256 + col)) * LQP + q) = u;
                    }
                }
        }
    }
}

// -------------------- MFMA flash self-attention ------------------------------
__global__ __launch_bounds__(256) void flash_mfma(const unsigned short* __restrict__ qk,
                                                  const unsigned short* __restrict__ vt,
                                                  unsigned short* __restrict__ out) {
    __shared__ unsigned short P_lds[4][16][72];
    int t = threadIdx.x;
    int l = t & 63, w = t >> 6;
    int lr = l & 15, lg = l >> 4;
    int qt = blockIdx.x, h = blockIdx.y, b = blockIdx.z;
    const float scale = 0.17677669529663687f;

    short8 qf = *(const short8*)(qk + (size_t)(b * LQm + qt * 64 + w * 16 + lr) * 512 + h * 32 + lg * 8);

    f32x4 accO[2];
    accO[0] = (f32x4){0.f, 0.f, 0.f, 0.f};
    accO[1] = (f32x4){0.f, 0.f, 0.f, 0.f};
    float mrow[4] = {-1e30f, -1e30f, -1e30f, -1e30f};
    float lrow[4] = {0.f, 0.f, 0.f, 0.f};
    const f32x4 zero = (f32x4){0.f, 0.f, 0.f, 0.f};
    const unsigned short* vtb = vt + ((size_t)(b * 256 + h * 32)) * LQP;

    for (int kt = 0; kt < 15; ++kt) {
        int k0 = kt * 64;
        f32x4 sfr[4];
        #pragma unroll
        for (int ks = 0; ks < 4; ++ks) {
            short8 kf = *(const short8*)(qk + (size_t)(b * LQm + k0 + ks * 16 + lr) * 512 + 256 + h * 32 + lg * 8);
            sfr[ks] = __builtin_amdgcn_mfma_f32_16x16x32_bf16(qf, kf, zero, 0, 0, 0);
        }
        float sv[4][4];
        #pragma unroll
        for (int ks = 0; ks < 4; ++ks) {
            bool valid = (k0 + ks * 16 + lr) < LQm;
            #pragma unroll
            for (int j = 0; j < 4; ++j)
                sv[ks][j] = valid ? sfr[ks][j] * scale : -1e30f;
        }
        float tm[4], newm[4], rr[4], ps[4];
        #pragma unroll
        for (int j = 0; j < 4; ++j)
            tm[j] = fmaxf(fmaxf(sv[0][j], sv[1][j]), fmaxf(sv[2][j], sv[3][j]));
        #pragma unroll
        for (int msk = 1; msk <= 8; msk <<= 1) {
            #pragma unroll
            for (int j = 0; j < 4; ++j) tm[j] = fmaxf(tm[j], __shfl_xor(tm[j], msk));
        }
        #pragma unroll
        for (int j = 0; j < 4; ++j) {
            newm[j] = fmaxf(mrow[j], tm[j]);
            rr[j] = __expf(mrow[j] - newm[j]);
            mrow[j] = newm[j];
            ps[j] = 0.f;
        }
        float pv[4][4];
        #pragma unroll
        for (int ks = 0; ks < 4; ++ks)
            #pragma unroll
            for (int j = 0; j < 4; ++j) {
                pv[ks][j] = __expf(sv[ks][j] - newm[j]);
                ps[j] += pv[ks][j];
            }
        #pragma unroll
        for (int msk = 1; msk <= 8; msk <<= 1) {
            #pragma unroll
            for (int j = 0; j < 4; ++j) ps[j] += __shfl_xor(ps[j], msk);
        }
        #pragma unroll
        for (int j = 0; j < 4; ++j) lrow[j] = lrow[j] * rr[j] + ps[j];
        #pragma unroll
        for (int n = 0; n < 2; ++n)
            #pragma unroll
            for (int j = 0; j < 4; ++j) accO[n][j] *= rr[j];
        #pragma unroll
        for (int ks = 0; ks < 4; ++ks)
            #pragma unroll
            for (int j = 0; j < 4; ++j)
                P_lds[w][lg * 4 + j][ks * 16 + lr] = f2bf(pv[ks][j]);
        #pragma unroll
        for (int kh2 = 0; kh2 < 2; ++kh2) {
            short8 pf = *(const short8*)(&P_lds[w][lr][kh2 * 32 + lg * 8]);
            #pragma unroll
            for (int n = 0; n < 2; ++n) {
                short8 vf = *(const short8*)(vtb + (size_t)(n * 16 + lr) * LQP + k0 + kh2 * 32 + lg * 8);
                accO[n] = __builtin_amdgcn_mfma_f32_16x16x32_bf16(pf, vf, accO[n], 0, 0, 0);
            }
        }
    }
    float inv[4];
    #pragma unroll
    for (int j = 0; j < 4; ++j) inv[j] = 1.0f / lrow[j];
    #pragma unroll
    for (int n = 0; n < 2; ++n)
        #pragma unroll
        for (int j = 0; j < 4; ++j) {
            int q = qt * 64 + w * 16 + lg * 4 + j;
            if (q < LQm)
                out[(size_t)(b * LQm + q) * 256 + h * 32 + n * 16 + lr] = f2bf(accO[n][j] * inv[j]);
        }
}

// -------------------- bf16 MFMA GEMM (tail: sa/offaw/op/ffn/ff) -------------
// OBF: 0 fp32 out, 1 bf16 out, 3 split (Cf ldc=256 / Cf2 ldc=128 at col 256)
template <int RELU, int OBF>
__global__ __launch_bounds__(256) void bgemm(int M, int N, int K,
        const unsigned short* __restrict__ A,
        const unsigned short* __restrict__ BT,
        const float* __restrict__ bias, const float* __restrict__ bias2,
        float* __restrict__ Cf, float* __restrict__ Cf2,
        unsigned short* __restrict__ Cb, int ldc) {
    __shared__ __align__(16) unsigned short As[2][128 * 32];
    __shared__ __align__(16) unsigned short Bs[2][128 * 32];
    int t = threadIdx.x;
    int l = t & 63;
    int w = t >> 6;
    int row0 = blockIdx.x * 128, col0 = blockIdx.y * 128;
    int wr = (w >> 1) * 64, wc = (w & 1) * 64;
    f32x4 acc[4][4];
    #pragma unroll
    for (int m = 0; m < 4; ++m)
        #pragma unroll
        for (int n = 0; n < 4; ++n) acc[m][n] = (f32x4){0.f, 0.f, 0.f, 0.f};

    int s0 = t, s1 = t + 256;
    const unsigned short* Ag = A + (size_t)row0 * K;
    const unsigned short* Bg = BT + (size_t)col0 * K;
    const unsigned short* a0p = Ag + (size_t)(s0 >> 2) * K + (s0 & 3) * 8;
    const unsigned short* a1p = Ag + (size_t)(s1 >> 2) * K + (s1 & 3) * 8;
    const unsigned short* b0p = Bg + (size_t)(s0 >> 2) * K + (s0 & 3) * 8;
    const unsigned short* b1p = Bg + (size_t)(s1 >> 2) * K + (s1 & 3) * 8;

    short8 ra0 = *(const short8*)(a0p);
    short8 ra1 = *(const short8*)(a1p);
    short8 rb0 = *(const short8*)(b0p);
    short8 rb1 = *(const short8*)(b1p);

    int cur = 0;
    for (int k0 = 0; k0 < K; k0 += 32) {
        unsigned short* Ac = As[cur];
        unsigned short* Bc = Bs[cur];
        *(short8*)(Ac + s0 * 8) = ra0;
        *(short8*)(Ac + s1 * 8) = ra1;
        *(short8*)(Bc + s0 * 8) = rb0;
        *(short8*)(Bc + s1 * 8) = rb1;
        if (k0 + 32 < K) {
            ra0 = *(const short8*)(a0p + k0 + 32);
            ra1 = *(const short8*)(a1p + k0 + 32);
            rb0 = *(const short8*)(b0p + k0 + 32);
            rb1 = *(const short8*)(b1p + k0 + 32);
        }
        __syncthreads();
        mfma_tilestep(Ac, Bc, wr, wc, l, acc);
        cur ^= 1;
    }

    int cr = (l >> 4) * 4;
    int cc = l & 15;
    #pragma unroll
    for (int m = 0; m < 4; ++m) {
        #pragma unroll
        for (int n = 0; n < 4; ++n) {
            int col = col0 + wc + n * 16 + cc;
            if (OBF == 3) {
                float bv = (col < 256) ? bias[col] : bias2[col - 256];
                #pragma unroll
                for (int j = 0; j < 4; ++j) {
                    int r = row0 + wr + m * 16 + cr + j;
                    if (r < M) {
                        float v = acc[m][n][j] + bv;
                        if (col < 256) Cf[(size_t)r * 256 + col] = v;
                        else           Cf2[(size_t)r * 128 + (col - 256)] = v;
                    }
                }
            } else {
                float bv = bias[col];
                #pragma unroll
                for (int j = 0; j < 4; ++j) {
                    int r = row0 + wr + m * 16 + cr + j;
                    if (r < M) {
                        float v = acc[m][n][j] + bv;
                        if (RELU) v = fmaxf(v, 0.f);
                        if (OBF) Cb[(size_t)r * ldc + col] = f2bf(v);
                        else     Cf[(size_t)r * ldc + col] = v;
                    }
                }
            }
        }
    }
}

// -------------------- fused residual add + LayerNorm (wave per row) ---------
template <int DUAL, int QP>
__global__ __launch_bounds__(256) void add_ln_kernel(const float* __restrict__ x,
                                                     const float* __restrict__ r,
                                                     const float* __restrict__ w,
                                                     const float* __restrict__ b,
                                                     const float* __restrict__ qpos,
                                                     float* __restrict__ out,
                                                     unsigned short* __restrict__ outb,
                                                     unsigned short* __restrict__ outq) {
    int row = blockIdx.x * 4 + (threadIdx.x >> 6);
    int lane = threadIdx.x & 63;
    size_t i4 = (size_t)row * 64 + lane;
    float4 xv = reinterpret_cast<const float4*>(x)[i4];
    float4 rv = reinterpret_cast<const float4*>(r)[i4];
    float4 v = make_float4(xv.x + rv.x, xv.y + rv.y, xv.z + rv.z, xv.w + rv.w);
    float s = v.x + v.y + v.z + v.w;
    #pragma unroll
    for (int msk = 1; msk <= 32; msk <<= 1) s += __shfl_xor(s, msk);
    float mean = s * (1.0f / Dm);
    float4 dv = make_float4(v.x - mean, v.y - mean, v.z - mean, v.w - mean);
    float sq = dv.x * dv.x + dv.y * dv.y + dv.z * dv.z + dv.w * dv.w;
    #pragma unroll
    for (int msk = 1; msk <= 32; msk <<= 1) sq += __shfl_xor(sq, msk);
    float is = rsqrtf(sq * (1.0f / Dm) + 1e-5f);
    float4 wv = reinterpret_cast<const float4*>(w)[lane];
    float4 bv = reinterpret_cast<const float4*>(b)[lane];
    float4 res = make_float4(dv.x * is * wv.x + bv.x, dv.y * is * wv.y + bv.y,
                             dv.z * is * wv.z + bv.z, dv.w * is * wv.w + bv.w);
    reinterpret_cast<float4*>(out)[i4] = res;
    if (DUAL) {
        ushort4 u;
        u.x = f2bf(res.x); u.y = f2bf(res.y); u.z = f2bf(res.z); u.w = f2bf(res.w);
        reinterpret_cast<ushort4*>(outb)[i4] = u;
    }
    if (QP) {
        float4 qv = reinterpret_cast<const float4*>(qpos)[i4];
        ushort4 u;
        u.x = f2bf(res.x + qv.x); u.y = f2bf(res.y + qv.y);
        u.z = f2bf(res.z + qv.z); u.w = f2bf(res.w + qv.w);
        reinterpret_cast<ushort4*>(outq)[i4] = u;
    }
}

// -------------------- ms-deformable sampling: wave per query ----------------
__global__ __launch_bounds__(256) void msdeform_kernel(const unsigned short* __restrict__ value,
                                                       const float* __restrict__ ref,
                                                       const float* __restrict__ off,
                                                       const float* __restrict__ awl,
                                                       unsigned short* __restrict__ out) {
    const int HL[4] = {100, 50, 25, 13};
    const int ST[4] = {0, 10000, 12500, 13125};
    __shared__ float lsx[4][128], lsy[4][128], wtab[4][128];
    __shared__ float2 ctab[4][512];
    int wv = threadIdx.x >> 6, lane = threadIdx.x & 63;
    int m = blockIdx.x * 4 + wv;
    int b = m / LQm;

    #pragma unroll
    for (int e = lane; e < 128; e += 64) {
        int lev = (e >> 2) & 3;
        float rx = ref[((size_t)m * NLEVm + lev) * 2 + 0];
        float ry = ref[((size_t)m * NLEVm + lev) * 2 + 1];
        float ox = off[(size_t)m * 256 + e * 2 + 0];
        float oy = off[(size_t)m * 256 + e * 2 + 1];
        float Wf = (float)HL[lev];
        lsx[wv][e] = (rx + ox / Wf) * Wf - 0.5f;
        lsy[wv][e] = (ry + oy / Wf) * Wf - 0.5f;
        wtab[wv][e] = awl[(size_t)m * 128 + e];
    }
    __syncthreads();
    if (lane < NHm) {
        int h = lane;
        float mx = -1e30f;
        #pragma unroll
        for (int i = 0; i < 16; i++) mx = fmaxf(mx, wtab[wv][h * 16 + i]);
        float s = 0.f;
        #pragma unroll
        for (int i = 0; i < 16; i++) {
            float e = __expf(wtab[wv][h * 16 + i] - mx);
            wtab[wv][h * 16 + i] = e; s += e;
        }
        float inv = 1.0f / s;
        #pragma unroll
        for (int i = 0; i < 16; i++) wtab[wv][h * 16 + i] *= inv;
    }
    __syncthreads();
    #pragma unroll
    for (int j = 0; j < 8; ++j) {
        int e2 = lane * 8 + j;
        int c = e2 & 3, e = e2 >> 2;
        int lev = (e >> 2) & 3;
        int Wl = HL[lev];
        float lx = lsx[wv][e], ly = lsy[wv][e];
        float x0f = floorf(lx), y0f = floorf(ly);
        float fx = lx - x0f, fy = ly - y0f;
        int dx = c & 1, dy = c >> 1;
        int xi = (int)x0f + dx, yi = (int)y0f + dy;
        bool valid = (xi >= 0) && (xi < Wl) && (yi >= 0) && (yi < Wl);
        float wc = valid ? ((dx ? fx : 1.0f - fx) * (dy ? fy : 1.0f - fy)) * wtab[wv][e] : 0.f;
        int xc = min(max(xi, 0), Wl - 1), yc = min(max(yi, 0), Wl - 1);
        int row = b * LENm + ST[lev] + yc * Wl + xc;
        ctab[wv][e2] = make_float2(__int_as_float(row), wc);
    }
    __syncthreads();
    int h = lane >> 3, dg = lane & 7;
    const unsigned short* basep = value + h * 32 + dg * 4;
    float a0 = 0.f, a1 = 0.f, a2 = 0.f, a3 = 0.f;
    #pragma unroll
    for (int i = 0; i < 16; ++i) {
        #pragma unroll
        for (int c = 0; c < 4; ++c) {
            float2 cc = ctab[wv][(h * 16 + i) * 4 + c];
            int row = __float_as_int(cc.x);
            float wc = cc.y;
            ushort4 v = *reinterpret_cast<const ushort4*>(basep + (size_t)row * 256);
            a0 += wc * bf2f(v.x); a1 += wc * bf2f(v.y);
            a2 += wc * bf2f(v.z); a3 += wc * bf2f(v.w);
        }
    }
    ushort4 o;
    o.x = f2bf(a0); o.y = f2bf(a1); o.z = f2bf(a2); o.w = f2bf(a3);
    *reinterpret_cast<ushort4*>(out + (size_t)m * 256 + h * 32 + dg * 4) = o;
}

// ------------------------------------------------------------------
extern "C" void kernel_launch(void* const* d_in, const int* in_sizes, int n_in,
                              void* d_out, int out_size, void* d_ws, size_t ws_size,
                              hipStream_t stream) {
    const float* tgt   = (const float*)d_in[0];
    const float* qpos  = (const float*)d_in[1];
    const float* refp  = (const float*)d_in[2];
    const float* src   = (const float*)d_in[3];
    const float* qkv_w = (const float*)d_in[6];
    const float* qkv_b = (const float*)d_in[7];
    const float* out_w = (const float*)d_in[8];
    const float* out_b = (const float*)d_in[9];
    const float* ln2_w = (const float*)d_in[10];
    const float* ln2_b = (const float*)d_in[11];
    const float* val_w = (const float*)d_in[12];
    const float* val_b = (const float*)d_in[13];
    const float* off_w = (const float*)d_in[14];
    const float* off_b = (const float*)d_in[15];
    const float* aw_w  = (const float*)d_in[16];
    const float* aw_b  = (const float*)d_in[17];
    const float* op_w  = (const float*)d_in[18];
    const float* op_b  = (const float*)d_in[19];
    const float* ln1_w = (const float*)d_in[20];
    const float* ln1_b = (const float*)d_in[21];
    const float* w1    = (const float*)d_in[22];
    const float* b1    = (const float*)d_in[23];
    const float* w2    = (const float*)d_in[24];
    const float* b2    = (const float*)d_in[25];
    const float* ln3_w = (const float*)d_in[26];
    const float* ln3_b = (const float*)d_in[27];

    char* base = (char*)d_ws;
    unsigned short* value_bf  = (unsigned short*)(base);                      // 54,460,416
    unsigned short* hidden_bf = (unsigned short*)(base + 54460416);
    unsigned short* t2_bf     = (unsigned short*)(base + 54460416 + 14942208);
    unsigned short* qk_bf = (unsigned short*)(base + 108920832);
    float* offb = (float*)(base + 108920832);                                 // aliases qk_bf (after flash)
    float* awb  = (float*)(base + 108920832 + 7372800);
    unsigned short* Vt = (unsigned short*)(base + 123666432);
    float* S1   = (float*)(base + 123666432);                                 // aliases Vt (after flash)
    float* t1   = (float*)(base + 131039232);
    float* t2   = (float*)(base + 138412032);
    unsigned short* Qbf     = (unsigned short*)(base + 145784832);
    unsigned short* tgt_bf  = (unsigned short*)(base + 149520384);
    unsigned short* attn_bf = (unsigned short*)(base + 153255936);
    unsigned short* ca_bf   = (unsigned short*)(base + 156991488);
    unsigned short* BT_qkv  = (unsigned short*)(base + 160727040);
    unsigned short* BT_out  = BT_qkv + 768 * 256;
    unsigned short* BT_val  = BT_out + 256 * 256;
    unsigned short* BT_off  = BT_val + 256 * 256;
    unsigned short* BT_aw   = BT_off + 256 * 256;                             // contiguous after BT_off
    unsigned short* BT_op   = BT_aw + 128 * 256;
    unsigned short* BT_w1   = BT_op + 256 * 256;
    unsigned short* BT_w2   = BT_w1 + 1024 * 256;
    float* outp = (float*)d_out;

    dim3 blk(256);
    // L1: weight transposes + prep
    wt_prep<<<dim3(2072), blk, 0, stream>>>(qkv_w, out_w, val_w, off_w, aw_w, op_w, w1, w2,
                                            BT_qkv, BT_out, BT_val, BT_off, BT_aw, BT_op, BT_w1, BT_w2,
                                            tgt, qpos, tgt_bf, Qbf);
    // L2: value(3324, 64x128 tiles) + qkh(456) + Vt(228) + vtpad(480)
    fused_gemms<<<dim3(4488), blk, 0, stream>>>(src, BT_val, val_b, value_bf,
                                                Qbf, BT_qkv, qkv_b, qk_bf, tgt_bf, Vt);
    // L3: flash attention
    flash_mfma<<<dim3(15, NHm, Bm), blk, 0, stream>>>(qk_bf, Vt, attn_bf);
    // L4: sa proj -> S1
    bgemm<0, 0><<<dim3(57, 2), blk, 0, stream>>>(MQ, 256, 256, attn_bf, BT_out, out_b, nullptr, S1, nullptr, nullptr, 256);
    // L5: t1 = LN(tgt + sa; ln2); Qbf = bf16(t1 + qpos)
    add_ln_kernel<0, 1><<<dim3(1800), blk, 0, stream>>>(tgt, S1, ln2_w, ln2_b, qpos, t1, nullptr, Qbf);
    // L6: fused off+aw projection
    bgemm<0, 3><<<dim3(57, 3), blk, 0, stream>>>(MQ, 384, 256, Qbf, BT_off, off_b, aw_b, offb, awb, nullptr, 0);
    // L7: msdeform -> ca_bf
    msdeform_kernel<<<dim3(1800), blk, 0, stream>>>(value_bf, refp, offb, awb, ca_bf);
    // L8: op proj -> S1
    bgemm<0, 0><<<dim3(57, 2), blk, 0, stream>>>(MQ, 256, 256, ca_bf, BT_op, op_b, nullptr, S1, nullptr, nullptr, 256);
    // L9: t2 = LN(t1 + ca; ln1) -> t2 + t2_bf
    add_ln_kernel<1, 0><<<dim3(1800), blk, 0, stream>>>(t1, S1, ln1_w, ln1_b, nullptr, t2, t2_bf, nullptr);
    // L10: ffn hidden
    bgemm<1, 1><<<dim3(57, 8), blk, 0, stream>>>(MQ, DFFNm, 256, t2_bf, BT_w1, b1, nullptr, nullptr, nullptr, hidden_bf, DFFNm);
    // L11: ff
    bgemm<0, 0><<<dim3(57, 2), blk, 0, stream>>>(MQ, 256, 1024, hidden_bf, BT_w2, b2, nullptr, S1, nullptr, nullptr, 256);
    // L12: out = LN(t2 + ff; ln3)
    add_ln_kernel<0, 0><<<dim3(1800), blk, 0, stream>>>(t2, S1, ln3_w, ln3_b, nullptr, outp, nullptr, nullptr);
}

// Round 15
// 237.031 us; speedup vs baseline: 1.0956x; 1.0254x over previous
//
#include <hip/hip_runtime.h>
#include <math.h>

#define Dm    256
#define NHm   8
#define DHm   32
#define NLEVm 4
#define NPTSm 4
#define DFFNm 1024
#define Bm    8
#define LQm   900
#define LENm  13294
#define MQ    (Bm * LQm)      // 7200
#define MV    (Bm * LENm)     // 106352
#define MQP   7296            // MQ padded to 128
#define MVP   106368          // MV padded to 128
#define LQP   960             // keys padded to 15*64

typedef __attribute__((ext_vector_type(8))) short short8;   // 8 bf16 (4 VGPRs)
typedef __attribute__((ext_vector_type(4))) float f32x4;    // MFMA acc

__device__ __forceinline__ unsigned short f2bf(float f) {
    unsigned int b = __float_as_uint(f);
    unsigned int r = (b + 0x7FFFu + ((b >> 16) & 1u)) >> 16;
    return (unsigned short)r;
}
__device__ __forceinline__ float bf2f(unsigned short u) {
    return __uint_as_float(((unsigned int)u) << 16);
}

// -------------------- fused weight transposes + prep (one launch) -----------
__device__ __forceinline__ void wt_tile(const float* __restrict__ W,
                                        unsigned short* __restrict__ BT,
                                        int N, int K, int n0, int k0, int t,
                                        float (*tile)[65]) {
    #pragma unroll
    for (int r0 = 0; r0 < 64; r0 += 16) {
        int r = r0 + (t >> 4);
        int c = (t & 15) * 4;
        float4 v = *reinterpret_cast<const float4*>(W + (size_t)(k0 + r) * N + n0 + c);
        tile[r][c + 0] = v.x; tile[r][c + 1] = v.y; tile[r][c + 2] = v.z; tile[r][c + 3] = v.w;
    }
    __syncthreads();
    #pragma unroll
    for (int s = t; s < 512; s += 256) {
        int r = s >> 3, c8 = (s & 7) * 8;
        short8 u;
        #pragma unroll
        for (int j = 0; j < 8; ++j) u[j] = (short)f2bf(tile[c8 + j][r]);
        *reinterpret_cast<short8*>(BT + (size_t)(n0 + r) * K + k0 + c8) = u;
    }
}

__global__ __launch_bounds__(256) void wt_prep(
        const float* __restrict__ qkv_w, const float* __restrict__ out_w,
        const float* __restrict__ val_w, const float* __restrict__ off_w,
        const float* __restrict__ aw_w,  const float* __restrict__ op_w,
        const float* __restrict__ w1,    const float* __restrict__ w2,
        unsigned short* __restrict__ BT_qkv, unsigned short* __restrict__ BT_out,
        unsigned short* __restrict__ BT_val, unsigned short* __restrict__ BT_off,
        unsigned short* __restrict__ BT_aw,  unsigned short* __restrict__ BT_op,
        unsigned short* __restrict__ BT_w1,  unsigned short* __restrict__ BT_w2,
        const float* __restrict__ tgt, const float* __restrict__ qpos,
        unsigned short* __restrict__ tgtb, unsigned short* __restrict__ qb) {
    __shared__ float tile[64][65];
    int bid = blockIdx.x;
    int t = threadIdx.x;
    if (bid >= 248) {                        // prep: tgt_bf + Qbf
        int i = (bid - 248) * 256 + t;       // < 466944 = MQP*64
        ushort4 ut, uq;
        if (i < MQ * 64) {
            float4 x = reinterpret_cast<const float4*>(tgt)[i];
            float4 y = reinterpret_cast<const float4*>(qpos)[i];
            ut.x = f2bf(x.x); ut.y = f2bf(x.y); ut.z = f2bf(x.z); ut.w = f2bf(x.w);
            uq.x = f2bf(x.x + y.x); uq.y = f2bf(x.y + y.y);
            uq.z = f2bf(x.z + y.z); uq.w = f2bf(x.w + y.w);
        } else {
            ut.x = ut.y = ut.z = ut.w = 0;
            uq.x = uq.y = uq.z = uq.w = 0;
        }
        reinterpret_cast<ushort4*>(tgtb)[i] = ut;
        reinterpret_cast<ushort4*>(qb)[i] = uq;
        return;
    }
    const float* W; unsigned short* BT; int N, K, idx;
    if      (bid < 48)  { W = qkv_w; BT = BT_qkv; N = 768;  K = 256;  idx = bid; }
    else if (bid < 64)  { W = out_w; BT = BT_out; N = 256;  K = 256;  idx = bid - 48; }
    else if (bid < 80)  { W = val_w; BT = BT_val; N = 256;  K = 256;  idx = bid - 64; }
    else if (bid < 96)  { W = off_w; BT = BT_off; N = 256;  K = 256;  idx = bid - 80; }
    else if (bid < 104) { W = aw_w;  BT = BT_aw;  N = 128;  K = 256;  idx = bid - 96; }
    else if (bid < 120) { W = op_w;  BT = BT_op;  N = 256;  K = 256;  idx = bid - 104; }
    else if (bid < 184) { W = w1;    BT = BT_w1;  N = 1024; K = 256;  idx = bid - 120; }
    else                { W = w2;    BT = BT_w2;  N = 256;  K = 1024; idx = bid - 184; }
    int nt = N / 64;
    int n0 = (idx % nt) * 64, k0 = (idx / nt) * 64;
    wt_tile(W, BT, N, K, n0, k0, t, tile);
}

// -------------------- 4x4 MFMA tile step (128-wide tiles, tail GEMMs) -------
__device__ __forceinline__ void mfma_tilestep(const unsigned short* Ac, const unsigned short* Bc,
                                              int wr, int wc, int l, f32x4 acc[4][4]) {
    short8 af[4], bfr[4];
    #pragma unroll
    for (int m = 0; m < 4; ++m)
        af[m] = *(const short8*)(Ac + (wr + m * 16 + (l & 15)) * 32 + (l >> 4) * 8);
    #pragma unroll
    for (int n = 0; n < 4; ++n)
        bfr[n] = *(const short8*)(Bc + (wc + n * 16 + (l & 15)) * 32 + (l >> 4) * 8);
    #pragma unroll
    for (int m = 0; m < 4; ++m)
        #pragma unroll
        for (int n = 0; n < 4; ++n)
            acc[m][n] = __builtin_amdgcn_mfma_f32_16x16x32_bf16(af[m], bfr[n], acc[m][n], 0, 0, 0);
}

// -------------------- 64x128 single-buffer GEMM core ------------------------
__device__ __forceinline__ void gemm64_core(int t, unsigned short* Sh,
                                            short8& ra, short8& rb0, short8& rb1,
                                            const unsigned short* ap,
                                            const unsigned short* b0p, const unsigned short* b1p,
                                            const float* afp, f32x4 acc[2][4]) {
    int l = t & 63;
    int lr = l & 15, lg = l >> 4;
    int w = t >> 6;
    int wr = (w >> 1) * 32, wc = (w & 1) * 64;
    unsigned short* As = Sh;
    unsigned short* Bs = Sh + 2048;
    for (int k0 = 0; k0 < 256; k0 += 32) {
        __syncthreads();                     // previous compute done
        *(short8*)(As + t * 8) = ra;
        *(short8*)(Bs + t * 8) = rb0;
        *(short8*)(Bs + (t + 256) * 8) = rb1;
        __syncthreads();                     // tile ready
        if (k0 + 32 < 256) {
            if (afp) {
                float4 f0 = *(const float4*)(afp + k0 + 32);
                float4 f1 = *(const float4*)(afp + k0 + 36);
                ra[0] = (short)f2bf(f0.x); ra[1] = (short)f2bf(f0.y);
                ra[2] = (short)f2bf(f0.z); ra[3] = (short)f2bf(f0.w);
                ra[4] = (short)f2bf(f1.x); ra[5] = (short)f2bf(f1.y);
                ra[6] = (short)f2bf(f1.z); ra[7] = (short)f2bf(f1.w);
            } else {
                ra = *(const short8*)(ap + k0 + 32);
            }
            rb0 = *(const short8*)(b0p + k0 + 32);
            rb1 = *(const short8*)(b1p + k0 + 32);
        }
        short8 af[2], bfr[4];
        #pragma unroll
        for (int m = 0; m < 2; ++m)
            af[m] = *(const short8*)(As + (wr + m * 16 + lr) * 32 + lg * 8);
        #pragma unroll
        for (int n = 0; n < 4; ++n)
            bfr[n] = *(const short8*)(Bs + (wc + n * 16 + lr) * 32 + lg * 8);
        #pragma unroll
        for (int m = 0; m < 2; ++m)
            #pragma unroll
            for (int n = 0; n < 4; ++n)
                acc[m][n] = __builtin_amdgcn_mfma_f32_16x16x32_bf16(af[m], bfr[n], acc[m][n], 0, 0, 0);
    }
}

// -------------------- value tile (64x128, fp32 A) ---------------------------
__device__ __forceinline__ void value_tile64(int vbid, int t, const float* __restrict__ src,
        const unsigned short* __restrict__ BT_val, const float* __restrict__ val_b,
        unsigned short* __restrict__ value_bf, unsigned short* Sh) {
    int l = t & 63, w = t >> 6;
    int lr = l & 15, lg = l >> 4;
    int wr = (w >> 1) * 32, wc = (w & 1) * 64;
    int cr = lg * 4, cc = lr;
    int row0 = (vbid % 1662) * 64, col0 = (vbid / 1662) * 128;
    f32x4 acc[2][4];
    #pragma unroll
    for (int m = 0; m < 2; ++m)
        #pragma unroll
        for (int n = 0; n < 4; ++n) acc[m][n] = (f32x4){0.f, 0.f, 0.f, 0.f};
    int rA = min(row0 + (t >> 2), MV - 1);               // clamp: src unpadded
    const float* afp = src + (size_t)rA * 256 + (t & 3) * 8;
    const unsigned short* Bg = BT_val + (size_t)col0 * 256;
    const unsigned short* b0p = Bg + (size_t)(t >> 2) * 256 + (t & 3) * 8;
    const unsigned short* b1p = Bg + (size_t)((t + 256) >> 2) * 256 + ((t + 256) & 3) * 8;
    short8 ra, rb0, rb1;
    {
        float4 f0 = *(const float4*)(afp);
        float4 f1 = *(const float4*)(afp + 4);
        ra[0] = (short)f2bf(f0.x); ra[1] = (short)f2bf(f0.y);
        ra[2] = (short)f2bf(f0.z); ra[3] = (short)f2bf(f0.w);
        ra[4] = (short)f2bf(f1.x); ra[5] = (short)f2bf(f1.y);
        ra[6] = (short)f2bf(f1.z); ra[7] = (short)f2bf(f1.w);
    }
    rb0 = *(const short8*)(b0p);
    rb1 = *(const short8*)(b1p);
    gemm64_core(t, Sh, ra, rb0, rb1, nullptr, b0p, b1p, afp, acc);
    #pragma unroll
    for (int m = 0; m < 2; ++m)
        #pragma unroll
        for (int n = 0; n < 4; ++n) {
            int col = col0 + wc + n * 16 + cc;
            float bv = val_b[col];
            #pragma unroll
            for (int j = 0; j < 4; ++j) {
                int r = row0 + wr + m * 16 + cr + j;
                if (r < MV)
                    value_bf[(size_t)r * 256 + col] = f2bf(acc[m][n][j] + bv);
            }
        }
}

// -------------------- flash attention block (flat sid) ----------------------
__device__ __forceinline__ void flash_block(int sid, int t,
        const unsigned short* __restrict__ qk, const unsigned short* __restrict__ vt,
        unsigned short* __restrict__ out, unsigned short* P_lds /* >= 4608 ushorts */) {
    int l = t & 63, w = t >> 6;
    int lr = l & 15, lg = l >> 4;
    int qt = sid % 15, h = (sid / 15) % 8, b = sid / 120;
    const float scale = 0.17677669529663687f;
    unsigned short* Pw = P_lds + w * 1152;   // [16][72]

    short8 qf = *(const short8*)(qk + (size_t)(b * LQm + qt * 64 + w * 16 + lr) * 512 + h * 32 + lg * 8);

    f32x4 accO[2];
    accO[0] = (f32x4){0.f, 0.f, 0.f, 0.f};
    accO[1] = (f32x4){0.f, 0.f, 0.f, 0.f};
    float mrow[4] = {-1e30f, -1e30f, -1e30f, -1e30f};
    float lrow[4] = {0.f, 0.f, 0.f, 0.f};
    const f32x4 zero = (f32x4){0.f, 0.f, 0.f, 0.f};
    const unsigned short* vtb = vt + ((size_t)(b * 256 + h * 32)) * LQP;

    for (int kt = 0; kt < 15; ++kt) {
        int k0 = kt * 64;
        f32x4 sfr[4];
        #pragma unroll
        for (int ks = 0; ks < 4; ++ks) {
            short8 kf = *(const short8*)(qk + (size_t)(b * LQm + k0 + ks * 16 + lr) * 512 + 256 + h * 32 + lg * 8);
            sfr[ks] = __builtin_amdgcn_mfma_f32_16x16x32_bf16(qf, kf, zero, 0, 0, 0);
        }
        float sv[4][4];
        #pragma unroll
        for (int ks = 0; ks < 4; ++ks) {
            bool valid = (k0 + ks * 16 + lr) < LQm;
            #pragma unroll
            for (int j = 0; j < 4; ++j)
                sv[ks][j] = valid ? sfr[ks][j] * scale : -1e30f;
        }
        float tm[4], newm[4], rr[4], ps[4];
        #pragma unroll
        for (int j = 0; j < 4; ++j)
            tm[j] = fmaxf(fmaxf(sv[0][j], sv[1][j]), fmaxf(sv[2][j], sv[3][j]));
        #pragma unroll
        for (int msk = 1; msk <= 8; msk <<= 1) {
            #pragma unroll
            for (int j = 0; j < 4; ++j) tm[j] = fmaxf(tm[j], __shfl_xor(tm[j], msk));
        }
        #pragma unroll
        for (int j = 0; j < 4; ++j) {
            newm[j] = fmaxf(mrow[j], tm[j]);
            rr[j] = __expf(mrow[j] - newm[j]);
            mrow[j] = newm[j];
            ps[j] = 0.f;
        }
        float pv[4][4];
        #pragma unroll
        for (int ks = 0; ks < 4; ++ks)
            #pragma unroll
            for (int j = 0; j < 4; ++j) {
                pv[ks][j] = __expf(sv[ks][j] - newm[j]);
                ps[j] += pv[ks][j];
            }
        #pragma unroll
        for (int msk = 1; msk <= 8; msk <<= 1) {
            #pragma unroll
            for (int j = 0; j < 4; ++j) ps[j] += __shfl_xor(ps[j], msk);
        }
        #pragma unroll
        for (int j = 0; j < 4; ++j) lrow[j] = lrow[j] * rr[j] + ps[j];
        #pragma unroll
        for (int n = 0; n < 2; ++n)
            #pragma unroll
            for (int j = 0; j < 4; ++j) accO[n][j] *= rr[j];
        #pragma unroll
        for (int ks = 0; ks < 4; ++ks)
            #pragma unroll
            for (int j = 0; j < 4; ++j)
                Pw[(lg * 4 + j) * 72 + ks * 16 + lr] = f2bf(pv[ks][j]);
        #pragma unroll
        for (int kh2 = 0; kh2 < 2; ++kh2) {
            short8 pf = *(const short8*)(Pw + lr * 72 + kh2 * 32 + lg * 8);
            #pragma unroll
            for (int n = 0; n < 2; ++n) {
                short8 vf = *(const short8*)(vtb + (size_t)(n * 16 + lr) * LQP + k0 + kh2 * 32 + lg * 8);
                accO[n] = __builtin_amdgcn_mfma_f32_16x16x32_bf16(pf, vf, accO[n], 0, 0, 0);
            }
        }
    }
    float inv[4];
    #pragma unroll
    for (int j = 0; j < 4; ++j) inv[j] = 1.0f / lrow[j];
    #pragma unroll
    for (int n = 0; n < 2; ++n)
        #pragma unroll
        for (int j = 0; j < 4; ++j) {
            int q = qt * 64 + w * 16 + lg * 4 + j;
            if (q < LQm)
                out[(size_t)(b * LQm + q) * 256 + h * 32 + n * 16 + lr] = f2bf(accO[n][j] * inv[j]);
        }
}

// -------------------- L2: qkh + Vt + vtpad ----------------------------------
// blocks: [0,456) qkh; [456,684) Vt; [684,1164) vtpad. 64x128 tiles.
__global__ __launch_bounds__(256) void qkvt_kernel(
        const unsigned short* __restrict__ Qbf, const unsigned short* __restrict__ BT_qkv,
        const float* __restrict__ qkv_b, unsigned short* __restrict__ qk_bf,
        const unsigned short* __restrict__ tgt_bf, unsigned short* __restrict__ Vt) {
    __shared__ __align__(16) unsigned short Sh[6144];
    int bid = blockIdx.x;
    int t = threadIdx.x;
    if (bid >= 684) {                        // vtpad
        int i = (bid - 684) * 256 + t;       // 480*256 = 122880 = 2048*60
        int row = i / 60, c = 900 + (i % 60);
        Vt[(size_t)row * LQP + c] = 0;
        return;
    }
    int l = t & 63, w = t >> 6;
    int lr = l & 15, lg = l >> 4;
    int wr = (w >> 1) * 32, wc = (w & 1) * 64;
    int cr = lg * 4, cc = lr;
    f32x4 acc[2][4];
    #pragma unroll
    for (int m = 0; m < 2; ++m)
        #pragma unroll
        for (int n = 0; n < 4; ++n) acc[m][n] = (f32x4){0.f, 0.f, 0.f, 0.f};

    bool is_qk = (bid < 456);
    int idx = is_qk ? bid : (bid - 456);
    int row0 = (idx % 114) * 64;
    int col0 = (idx / 114) * 128;
    const unsigned short* A  = is_qk ? Qbf : tgt_bf;
    const unsigned short* BT = is_qk ? BT_qkv : (BT_qkv + 512 * 256);
    const float* bias        = is_qk ? qkv_b : (qkv_b + 512);
    const unsigned short* ap  = A  + (size_t)(row0 + (t >> 2)) * 256 + (t & 3) * 8;
    const unsigned short* Bg  = BT + (size_t)col0 * 256;
    const unsigned short* b0p = Bg + (size_t)(t >> 2) * 256 + (t & 3) * 8;
    const unsigned short* b1p = Bg + (size_t)((t + 256) >> 2) * 256 + ((t + 256) & 3) * 8;
    short8 ra = *(const short8*)(ap);
    short8 rb0 = *(const short8*)(b0p);
    short8 rb1 = *(const short8*)(b1p);
    gemm64_core(t, Sh, ra, rb0, rb1, ap, b0p, b1p, nullptr, acc);
    if (is_qk) {
        #pragma unroll
        for (int m = 0; m < 2; ++m)
            #pragma unroll
            for (int n = 0; n < 4; ++n) {
                int col = col0 + wc + n * 16 + cc;
                float bv = bias[col];
                #pragma unroll
                for (int j = 0; j < 4; ++j) {
                    int r = row0 + wr + m * 16 + cr + j;
                    if (r < MQ)
                        qk_bf[(size_t)r * 512 + col] = f2bf(acc[m][n][j] + bv);
                }
            }
    } else {
        #pragma unroll
        for (int m = 0; m < 2; ++m)
            #pragma unroll
            for (int n = 0; n < 4; ++n) {
                int col = col0 + wc + n * 16 + cc;
                float bv = bias[col];
                int r0 = row0 + wr + m * 16 + cr;        // multiple of 4; 900%4==0
                if (r0 < MQ) {
                    int bb = r0 / 900;
                    int q = r0 - bb * 900;
                    ushort4 u;
                    u.x = f2bf(acc[m][n][0] + bv);
                    u.y = f2bf(acc[m][n][1] + bv);
                    u.z = f2bf(acc[m][n][2] + bv);
                    u.w = f2bf(acc[m][n][3] + bv);
                    *reinterpret_cast<ushort4*>(Vt + ((size_t)(bb * 256 + col)) * LQP + q) = u;
                }
            }
    }
}

// -------------------- L3: flash (960) + value (3324) co-scheduled -----------
__global__ __launch_bounds__(256) void flash_value(
        const unsigned short* __restrict__ qk_bf, const unsigned short* __restrict__ Vt,
        unsigned short* __restrict__ attn_bf,
        const float* __restrict__ src, const unsigned short* __restrict__ BT_val,
        const float* __restrict__ val_b, unsigned short* __restrict__ value_bf) {
    __shared__ __align__(16) unsigned short Sh[6144];    // 12 KB (flash uses 4608)
    int bid = blockIdx.x;
    int t = threadIdx.x;
    if (bid < 960) {
        flash_block(bid, t, qk_bf, Vt, attn_bf, Sh);
    } else {
        value_tile64(bid - 960, t, src, BT_val, val_b, value_bf, Sh);
    }
}

// -------------------- bf16 MFMA GEMM (tail: sa/offaw/op/ffn/ff) -------------
// OBF: 0 fp32 out, 1 bf16 out, 3 split (Cf ldc=256 / Cf2 ldc=128 at col 256)
template <int RELU, int OBF>
__global__ __launch_bounds__(256) void bgemm(int M, int N, int K,
        const unsigned short* __restrict__ A,
        const unsigned short* __restrict__ BT,
        const float* __restrict__ bias, const float* __restrict__ bias2,
        float* __restrict__ Cf, float* __restrict__ Cf2,
        unsigned short* __restrict__ Cb, int ldc) {
    __shared__ __align__(16) unsigned short As[2][128 * 32];
    __shared__ __align__(16) unsigned short Bs[2][128 * 32];
    int t = threadIdx.x;
    int l = t & 63;
    int w = t >> 6;
    int row0 = blockIdx.x * 128, col0 = blockIdx.y * 128;
    int wr = (w >> 1) * 64, wc = (w & 1) * 64;
    f32x4 acc[4][4];
    #pragma unroll
    for (int m = 0; m < 4; ++m)
        #pragma unroll
        for (int n = 0; n < 4; ++n) acc[m][n] = (f32x4){0.f, 0.f, 0.f, 0.f};

    int s0 = t, s1 = t + 256;
    const unsigned short* Ag = A + (size_t)row0 * K;
    const unsigned short* Bg = BT + (size_t)col0 * K;
    const unsigned short* a0p = Ag + (size_t)(s0 >> 2) * K + (s0 & 3) * 8;
    const unsigned short* a1p = Ag + (size_t)(s1 >> 2) * K + (s1 & 3) * 8;
    const unsigned short* b0p = Bg + (size_t)(s0 >> 2) * K + (s0 & 3) * 8;
    const unsigned short* b1p = Bg + (size_t)(s1 >> 2) * K + (s1 & 3) * 8;

    short8 ra0 = *(const short8*)(a0p);
    short8 ra1 = *(const short8*)(a1p);
    short8 rb0 = *(const short8*)(b0p);
    short8 rb1 = *(const short8*)(b1p);

    int cur = 0;
    for (int k0 = 0; k0 < K; k0 += 32) {
        unsigned short* Ac = As[cur];
        unsigned short* Bc = Bs[cur];
        *(short8*)(Ac + s0 * 8) = ra0;
        *(short8*)(Ac + s1 * 8) = ra1;
        *(short8*)(Bc + s0 * 8) = rb0;
        *(short8*)(Bc + s1 * 8) = rb1;
        if (k0 + 32 < K) {
            ra0 = *(const short8*)(a0p + k0 + 32);
            ra1 = *(const short8*)(a1p + k0 + 32);
            rb0 = *(const short8*)(b0p + k0 + 32);
            rb1 = *(const short8*)(b1p + k0 + 32);
        }
        __syncthreads();
        mfma_tilestep(Ac, Bc, wr, wc, l, acc);
        cur ^= 1;
    }

    int cr = (l >> 4) * 4;
    int cc = l & 15;
    #pragma unroll
    for (int m = 0; m < 4; ++m) {
        #pragma unroll
        for (int n = 0; n < 4; ++n) {
            int col = col0 + wc + n * 16 + cc;
            if (OBF == 3) {
                float bv = (col < 256) ? bias[col] : bias2[col - 256];
                #pragma unroll
                for (int j = 0; j < 4; ++j) {
                    int r = row0 + wr + m * 16 + cr + j;
                    if (r < M) {
                        float v = acc[m][n][j] + bv;
                        if (col < 256) Cf[(size_t)r * 256 + col] = v;
                        else           Cf2[(size_t)r * 128 + (col - 256)] = v;
                    }
                }
            } else {
                float bv = bias[col];
                #pragma unroll
                for (int j = 0; j < 4; ++j) {
                    int r = row0 + wr + m * 16 + cr + j;
                    if (r < M) {
                        float v = acc[m][n][j] + bv;
                        if (RELU) v = fmaxf(v, 0.f);
                        if (OBF) Cb[(size_t)r * ldc + col] = f2bf(v);
                        else     Cf[(size_t)r * ldc + col] = v;
                    }
                }
            }
        }
    }
}

// -------------------- fused residual add + LayerNorm (wave per row) ---------
template <int DUAL, int QP>
__global__ __launch_bounds__(256) void add_ln_kernel(const float* __restrict__ x,
                                                     const float* __restrict__ r,
                                                     const float* __restrict__ w,
                                                     const float* __restrict__ b,
                                                     const float* __restrict__ qpos,
                                                     float* __restrict__ out,
                                                     unsigned short* __restrict__ outb,
                                                     unsigned short* __restrict__ outq) {
    int row = blockIdx.x * 4 + (threadIdx.x >> 6);
    int lane = threadIdx.x & 63;
    size_t i4 = (size_t)row * 64 + lane;
    float4 xv = reinterpret_cast<const float4*>(x)[i4];
    float4 rv = reinterpret_cast<const float4*>(r)[i4];
    float4 v = make_float4(xv.x + rv.x, xv.y + rv.y, xv.z + rv.z, xv.w + rv.w);
    float s = v.x + v.y + v.z + v.w;
    #pragma unroll
    for (int msk = 1; msk <= 32; msk <<= 1) s += __shfl_xor(s, msk);
    float mean = s * (1.0f / Dm);
    float4 dv = make_float4(v.x - mean, v.y - mean, v.z - mean, v.w - mean);
    float sq = dv.x * dv.x + dv.y * dv.y + dv.z * dv.z + dv.w * dv.w;
    #pragma unroll
    for (int msk = 1; msk <= 32; msk <<= 1) sq += __shfl_xor(sq, msk);
    float is = rsqrtf(sq * (1.0f / Dm) + 1e-5f);
    float4 wv = reinterpret_cast<const float4*>(w)[lane];
    float4 bv = reinterpret_cast<const float4*>(b)[lane];
    float4 res = make_float4(dv.x * is * wv.x + bv.x, dv.y * is * wv.y + bv.y,
                             dv.z * is * wv.z + bv.z, dv.w * is * wv.w + bv.w);
    reinterpret_cast<float4*>(out)[i4] = res;
    if (DUAL) {
        ushort4 u;
        u.x = f2bf(res.x); u.y = f2bf(res.y); u.z = f2bf(res.z); u.w = f2bf(res.w);
        reinterpret_cast<ushort4*>(outb)[i4] = u;
    }
    if (QP) {
        float4 qv = reinterpret_cast<const float4*>(qpos)[i4];
        ushort4 u;
        u.x = f2bf(res.x + qv.x); u.y = f2bf(res.y + qv.y);
        u.z = f2bf(res.z + qv.z); u.w = f2bf(res.w + qv.w);
        reinterpret_cast<ushort4*>(outq)[i4] = u;
    }
}

// -------------------- ms-deformable sampling: wave per query ----------------
__global__ __launch_bounds__(256) void msdeform_kernel(const unsigned short* __restrict__ value,
                                                       const float* __restrict__ ref,
                                                       const float* __restrict__ off,
                                                       const float* __restrict__ awl,
                                                       unsigned short* __restrict__ out) {
    const int HL[4] = {100, 50, 25, 13};
    const int ST[4] = {0, 10000, 12500, 13125};
    __shared__ float lsx[4][128], lsy[4][128], wtab[4][128];
    __shared__ float2 ctab[4][512];
    int wv = threadIdx.x >> 6, lane = threadIdx.x & 63;
    int m = blockIdx.x * 4 + wv;
    int b = m / LQm;

    #pragma unroll
    for (int e = lane; e < 128; e += 64) {
        int lev = (e >> 2) & 3;
        float rx = ref[((size_t)m * NLEVm + lev) * 2 + 0];
        float ry = ref[((size_t)m * NLEVm + lev) * 2 + 1];
        float ox = off[(size_t)m * 256 + e * 2 + 0];
        float oy = off[(size_t)m * 256 + e * 2 + 1];
        float Wf = (float)HL[lev];
        lsx[wv][e] = (rx + ox / Wf) * Wf - 0.5f;
        lsy[wv][e] = (ry + oy / Wf) * Wf - 0.5f;
        wtab[wv][e] = awl[(size_t)m * 128 + e];
    }
    __syncthreads();
    if (lane < NHm) {
        int h = lane;
        float mx = -1e30f;
        #pragma unroll
        for (int i = 0; i < 16; i++) mx = fmaxf(mx, wtab[wv][h * 16 + i]);
        float s = 0.f;
        #pragma unroll
        for (int i = 0; i < 16; i++) {
            float e = __expf(wtab[wv][h * 16 + i] - mx);
            wtab[wv][h * 16 + i] = e; s += e;
        }
        float inv = 1.0f / s;
        #pragma unroll
        for (int i = 0; i < 16; i++) wtab[wv][h * 16 + i] *= inv;
    }
    __syncthreads();
    #pragma unroll
    for (int j = 0; j < 8; ++j) {
        int e2 = lane * 8 + j;
        int c = e2 & 3, e = e2 >> 2;
        int lev = (e >> 2) & 3;
        int Wl = HL[lev];
        float lx = lsx[wv][e], ly = lsy[wv][e];
        float x0f = floorf(lx), y0f = floorf(ly);
        float fx = lx - x0f, fy = ly - y0f;
        int dx = c & 1, dy = c >> 1;
        int xi = (int)x0f + dx, yi = (int)y0f + dy;
        bool valid = (xi >= 0) && (xi < Wl) && (yi >= 0) && (yi < Wl);
        float wc = valid ? ((dx ? fx : 1.0f - fx) * (dy ? fy : 1.0f - fy)) * wtab[wv][e] : 0.f;
        int xc = min(max(xi, 0), Wl - 1), yc = min(max(yi, 0), Wl - 1);
        int row = b * LENm + ST[lev] + yc * Wl + xc;
        ctab[wv][e2] = make_float2(__int_as_float(row), wc);
    }
    __syncthreads();
    int h = lane >> 3, dg = lane & 7;
    const unsigned short* basep = value + h * 32 + dg * 4;
    float a0 = 0.f, a1 = 0.f, a2 = 0.f, a3 = 0.f;
    #pragma unroll
    for (int i = 0; i < 16; ++i) {
        #pragma unroll
        for (int c = 0; c < 4; ++c) {
            float2 cc = ctab[wv][(h * 16 + i) * 4 + c];
            int row = __float_as_int(cc.x);
            float wc = cc.y;
            ushort4 v = *reinterpret_cast<const ushort4*>(basep + (size_t)row * 256);
            a0 += wc * bf2f(v.x); a1 += wc * bf2f(v.y);
            a2 += wc * bf2f(v.z); a3 += wc * bf2f(v.w);
        }
    }
    ushort4 o;
    o.x = f2bf(a0); o.y = f2bf(a1); o.z = f2bf(a2); o.w = f2bf(a3);
    *reinterpret_cast<ushort4*>(out + (size_t)m * 256 + h * 32 + dg * 4) = o;
}

// ------------------------------------------------------------------
extern "C" void kernel_launch(void* const* d_in, const int* in_sizes, int n_in,
                              void* d_out, int out_size, void* d_ws, size_t ws_size,
                              hipStream_t stream) {
    const float* tgt   = (const float*)d_in[0];
    const float* qpos  = (const float*)d_in[1];
    const float* refp  = (const float*)d_in[2];
    const float* src   = (const float*)d_in[3];
    const float* qkv_w = (const float*)d_in[6];
    const float* qkv_b = (const float*)d_in[7];
    const float* out_w = (const float*)d_in[8];
    const float* out_b = (const float*)d_in[9];
    const float* ln2_w = (const float*)d_in[10];
    const float* ln2_b = (const float*)d_in[11];
    const float* val_w = (const float*)d_in[12];
    const float* val_b = (const float*)d_in[13];
    const float* off_w = (const float*)d_in[14];
    const float* off_b = (const float*)d_in[15];
    const float* aw_w  = (const float*)d_in[16];
    const float* aw_b  = (const float*)d_in[17];
    const float* op_w  = (const float*)d_in[18];
    const float* op_b  = (const float*)d_in[19];
    const float* ln1_w = (const float*)d_in[20];
    const float* ln1_b = (const float*)d_in[21];
    const float* w1    = (const float*)d_in[22];
    const float* b1    = (const float*)d_in[23];
    const float* w2    = (const float*)d_in[24];
    const float* b2    = (const float*)d_in[25];
    const float* ln3_w = (const float*)d_in[26];
    const float* ln3_b = (const float*)d_in[27];

    char* base = (char*)d_ws;
    unsigned short* value_bf  = (unsigned short*)(base);                      // 54,460,416
    unsigned short* hidden_bf = (unsigned short*)(base + 54460416);
    unsigned short* t2_bf     = (unsigned short*)(base + 54460416 + 14942208);
    unsigned short* qk_bf = (unsigned short*)(base + 108920832);
    float* offb = (float*)(base + 108920832);                                 // aliases qk_bf (after flash)
    float* awb  = (float*)(base + 108920832 + 7372800);
    unsigned short* Vt = (unsigned short*)(base + 123666432);
    float* S1   = (float*)(base + 123666432);                                 // aliases Vt (after flash)
    float* t1   = (float*)(base + 131039232);
    float* t2   = (float*)(base + 138412032);
    unsigned short* Qbf     = (unsigned short*)(base + 145784832);
    unsigned short* tgt_bf  = (unsigned short*)(base + 149520384);
    unsigned short* attn_bf = (unsigned short*)(base + 153255936);
    unsigned short* ca_bf   = (unsigned short*)(base + 156991488);
    unsigned short* BT_qkv  = (unsigned short*)(base + 160727040);
    unsigned short* BT_out  = BT_qkv + 768 * 256;
    unsigned short* BT_val  = BT_out + 256 * 256;
    unsigned short* BT_off  = BT_val + 256 * 256;
    unsigned short* BT_aw   = BT_off + 256 * 256;                             // contiguous after BT_off
    unsigned short* BT_op   = BT_aw + 128 * 256;
    unsigned short* BT_w1   = BT_op + 256 * 256;
    unsigned short* BT_w2   = BT_w1 + 1024 * 256;
    float* outp = (float*)d_out;

    dim3 blk(256);
    // L1: weight transposes + prep
    wt_prep<<<dim3(2072), blk, 0, stream>>>(qkv_w, out_w, val_w, off_w, aw_w, op_w, w1, w2,
                                            BT_qkv, BT_out, BT_val, BT_off, BT_aw, BT_op, BT_w1, BT_w2,
                                            tgt, qpos, tgt_bf, Qbf);
    // L2: qkh(456) + Vt(228) + vtpad(480)
    qkvt_kernel<<<dim3(1164), blk, 0, stream>>>(Qbf, BT_qkv, qkv_b, qk_bf, tgt_bf, Vt);
    // L3: flash(960) + value(3324) co-scheduled
    flash_value<<<dim3(4284), blk, 0, stream>>>(qk_bf, Vt, attn_bf, src, BT_val, val_b, value_bf);
    // L4: sa proj -> S1
    bgemm<0, 0><<<dim3(57, 2), blk, 0, stream>>>(MQ, 256, 256, attn_bf, BT_out, out_b, nullptr, S1, nullptr, nullptr, 256);
    // L5: t1 = LN(tgt + sa; ln2); Qbf = bf16(t1 + qpos)
    add_ln_kernel<0, 1><<<dim3(1800), blk, 0, stream>>>(tgt, S1, ln2_w, ln2_b, qpos, t1, nullptr, Qbf);
    // L6: fused off+aw projection
    bgemm<0, 3><<<dim3(57, 3), blk, 0, stream>>>(MQ, 384, 256, Qbf, BT_off, off_b, aw_b, offb, awb, nullptr, 0);
    // L7: msdeform -> ca_bf
    msdeform_kernel<<<dim3(1800), blk, 0, stream>>>(value_bf, refp, offb, awb, ca_bf);
    // L8: op proj -> S1
    bgemm<0, 0><<<dim3(57, 2), blk, 0, stream>>>(MQ, 256, 256, ca_bf, BT_op, op_b, nullptr, S1, nullptr, nullptr, 256);
    // L9: t2 = LN(t1 + ca; ln1) -> t2 + t2_bf
    add_ln_kernel<1, 0><<<dim3(1800), blk, 0, stream>>>(t1, S1, ln1_w, ln1_b, nullptr, t2, t2_bf, nullptr);
    // L10: ffn hidden
    bgemm<1, 1><<<dim3(57, 8), blk, 0, stream>>>(MQ, DFFNm, 256, t2_bf, BT_w1, b1, nullptr, nullptr, nullptr, hidden_bf, DFFNm);
    // L11: ff
    bgemm<0, 0><<<dim3(57, 2), blk, 0, stream>>>(MQ, 256, 1024, hidden_bf, BT_w2, b2, nullptr, S1, nullptr, nullptr, 256);
    // L12: out = LN(t2 + ff; ln3)
    add_ln_kernel<0, 0><<<dim3(1800), blk, 0, stream>>>(t2, S1, ln3_w, ln3_b, nullptr, outp, nullptr, nullptr);
}